// Round 1
// baseline (2038.647 us; speedup 1.0000x reference)
//
#include <hip/hip_runtime.h>

// dims
static constexpr int CC = 128, NN = 16384;       // C, H*W (H=W=128)
static constexpr int O3 = 384;                   // 3*C
static constexpr long long CN  = (long long)CC * NN;   // 2097152
static constexpr long long O3N = (long long)O3 * NN;   // 6291456

__device__ __forceinline__ float wave_sum(float v) {
  for (int o = 32; o; o >>= 1) v += __shfl_xor(v, o);
  return v;
}
__device__ __forceinline__ float wave_max(float v) {
  for (int o = 32; o; o >>= 1) v = fmaxf(v, __shfl_xor(v, o));
  return v;
}

// ---- per-pixel LN stats over channels: mu, rstd ----
__global__ __launch_bounds__(256) void k_stats(const float* __restrict__ in,
                                               float* __restrict__ mu,
                                               float* __restrict__ rs) {
  int p = blockIdx.x * 256 + threadIdx.x;          // [0, B*N)
  int b = p >> 14, n = p & (NN - 1);
  const float* base = in + (size_t)b * CN + n;
  float s1 = 0.f, s2 = 0.f;
#pragma unroll 8
  for (int c = 0; c < CC; ++c) { float v = base[(size_t)c * NN]; s1 += v; s2 += v * v; }
  float m = s1 * (1.f / CC);
  float var = s2 * (1.f / CC) - m * m;
  mu[p] = m;
  rs[p] = rsqrtf(var + 1e-5f);
}

// ---- fused LN + 1x1 conv (qkv): out[bz,o,n] = sum_c W[o,c]*ln(x[bg,c,n]) + b[o] ----
__global__ __launch_bounds__(256) void k_conv_ln(
    const float* __restrict__ x, const float* __restrict__ mu, const float* __restrict__ rs,
    const float* __restrict__ lnw, const float* __restrict__ lnb,
    const float* __restrict__ wq, const float* __restrict__ bq,
    float* __restrict__ out, int b0) {
  __shared__ float As[64][33];
  __shared__ float Bs[32][128];
  int bz = blockIdx.z, bg = b0 + bz;
  int n0 = blockIdx.x * 128, o0 = blockIdx.y * 64;
  int t = threadIdx.x, to = t >> 4, tn = t & 15;
  const float* xb  = x  + (size_t)bg * CN + n0;
  const float* mub = mu + (size_t)bg * NN + n0;
  const float* rsb = rs + (size_t)bg * NN + n0;
  float acc[4][8];
#pragma unroll
  for (int i = 0; i < 4; ++i)
#pragma unroll
    for (int j = 0; j < 8; ++j) acc[i][j] = 0.f;

  for (int kk = 0; kk < 128; kk += 32) {
#pragma unroll
    for (int r = 0; r < 8; ++r) {
      int idx = r * 256 + t, m = idx >> 5, k2 = idx & 31;
      As[m][k2] = wq[(size_t)(o0 + m) * CC + kk + k2];
    }
#pragma unroll
    for (int r = 0; r < 16; ++r) {
      int idx = r * 256 + t, k2 = idx >> 7, n = idx & 127;
      int c = kk + k2;
      float v = xb[(size_t)c * NN + n];
      Bs[k2][n] = (v - mub[n]) * rsb[n] * lnw[c] + lnb[c];
    }
    __syncthreads();
#pragma unroll
    for (int k2 = 0; k2 < 32; ++k2) {
      float a0 = As[to * 4 + 0][k2], a1 = As[to * 4 + 1][k2];
      float a2 = As[to * 4 + 2][k2], a3 = As[to * 4 + 3][k2];
      const float4* bp = (const float4*)&Bs[k2][tn * 8];
      float4 b0v = bp[0], b1v = bp[1];
      float bv[8] = {b0v.x, b0v.y, b0v.z, b0v.w, b1v.x, b1v.y, b1v.z, b1v.w};
#pragma unroll
      for (int j = 0; j < 8; ++j) {
        acc[0][j] += a0 * bv[j]; acc[1][j] += a1 * bv[j];
        acc[2][j] += a2 * bv[j]; acc[3][j] += a3 * bv[j];
      }
    }
    __syncthreads();
  }
  float* ob = out + (size_t)bz * O3N + n0 + tn * 8;
#pragma unroll
  for (int i = 0; i < 4; ++i) {
    int o = o0 + to * 4 + i;
    float bias = bq[o];
    float4 v0 = make_float4(acc[i][0] + bias, acc[i][1] + bias, acc[i][2] + bias, acc[i][3] + bias);
    float4 v1 = make_float4(acc[i][4] + bias, acc[i][5] + bias, acc[i][6] + bias, acc[i][7] + bias);
    float4* dst = (float4*)(ob + (size_t)o * NN);
    dst[0] = v0; dst[1] = v1;
  }
}

// ---- 3x3 depthwise conv, pad 1 ----
__global__ __launch_bounds__(256) void k_dwc(const float* __restrict__ cin,
                                             const float* __restrict__ dww,
                                             const float* __restrict__ dwb,
                                             float* __restrict__ qout) {
  int bz = blockIdx.z, o = blockIdx.y;
  int n = blockIdx.x * 256 + threadIdx.x;
  int h = n >> 7, w = n & 127;
  const float* base = cin + (size_t)bz * O3N + (size_t)o * NN;
  const float* wg = dww + o * 9;
  float acc = dwb[o];
#pragma unroll
  for (int dy = -1; dy <= 1; ++dy) {
    int hh = h + dy;
    if ((unsigned)hh < 128u) {
#pragma unroll
      for (int dx = -1; dx <= 1; ++dx) {
        int ww2 = w + dx;
        if ((unsigned)ww2 < 128u) acc += base[hh * 128 + ww2] * wg[(dy + 1) * 3 + dx + 1];
      }
    }
  }
  qout[(size_t)bz * O3N + (size_t)o * NN + n] = acc;
}

// ---- stage-1 reductions: q mean over h, k max over h  -> [b, c, w] ----
__global__ __launch_bounds__(256) void k_reduce1(const float* __restrict__ qkv,
                                                 float* __restrict__ qm, float* __restrict__ km,
                                                 int b0) {
  int bz = blockIdx.y;
  int idx = blockIdx.x * 256 + threadIdx.x;   // c*128 + w
  int c = idx >> 7, w = idx & 127;
  const float* base = qkv + (size_t)bz * O3N;
  const float* q = base + (size_t)c * NN + w;
  const float* k = base + (size_t)(c + 128) * NN + w;
  float s = 0.f, mx = -1e30f;
#pragma unroll 4
  for (int h = 0; h < 128; ++h) { s += q[h * 128]; mx = fmaxf(mx, k[h * 128]); }
  size_t off = (size_t)(b0 + bz) * NN + idx;
  qm[off] = s * (1.f / 128.f);
  km[off] = mx;
}

// ---- stage-2 reductions: mean over channels -> [b, h, w] ----
__global__ __launch_bounds__(256) void k_reduce2(const float* __restrict__ qkv,
                                                 float* __restrict__ qm, float* __restrict__ km,
                                                 int b0) {
  int bz = blockIdx.y;
  int n = blockIdx.x * 256 + threadIdx.x;
  const float* base = qkv + (size_t)bz * O3N + n;
  float sq = 0.f, sk = 0.f;
#pragma unroll 4
  for (int c = 0; c < 128; ++c) { sq += base[(size_t)c * NN]; sk += base[(size_t)(c + 128) * NN]; }
  size_t off = (size_t)(b0 + bz) * NN + n;
  qm[off] = sq * (1.f / 128.f);
  km[off] = sk * (1.f / 128.f);
}

// ---- l2-normalize rows of length 128 in place ----
__global__ void k_norm_rows(float* __restrict__ buf, int row0) {
  int r = row0 + blockIdx.x, t = threadIdx.x;   // 64 threads
  float* p = buf + (size_t)r * 128;
  float v0 = p[t], v1 = p[t + 64];
  float s = wave_sum(v0 * v0 + v1 * v1);
  float sc = 1.f / fmaxf(sqrtf(s), 1e-12f);
  p[t] = v0 * sc;
  p[t + 64] = v1 * sc;
}

// ---- attn1[b,i,j] = softmax_j( sum_c qm[b,c,i]*km[b,c,j] * temp ) ----
__global__ void k_attn1(const float* __restrict__ qm, const float* __restrict__ km,
                        const float* __restrict__ temp, float* __restrict__ attn, int b0) {
  int bg = b0 + blockIdx.y;
  int i = blockIdx.x, t = threadIdx.x;          // 128 threads, t = j
  const float* qb = qm + (size_t)bg * NN;
  const float* kb = km + (size_t)bg * NN;
  __shared__ float qcol[128];
  __shared__ float wred[2];
  qcol[t] = qb[t * 128 + i];
  __syncthreads();
  float s = 0.f;
#pragma unroll 4
  for (int k = 0; k < 128; ++k) s += qcol[k] * kb[k * 128 + t];
  s *= temp[0];
  int wid = t >> 6, lane = t & 63;
  float mx = wave_max(s);
  if (lane == 0) wred[wid] = mx;
  __syncthreads();
  mx = fmaxf(wred[0], wred[1]);
  float pv = __expf(s - mx);
  __syncthreads();
  float sm = wave_sum(pv);
  if (lane == 0) wred[wid] = sm;
  __syncthreads();
  float denom = wred[0] + wred[1];
  attn[(size_t)bg * NN + i * 128 + t] = pv / denom;
}

// ---- attn2[b,h,g] = softmax_g( sum_w qm[b,h,w]*km[b,g,w] * temp ) ----
__global__ void k_attn2(const float* __restrict__ qm, const float* __restrict__ km,
                        const float* __restrict__ temp, float* __restrict__ attn, int b0) {
  int bg = b0 + blockIdx.y;
  int i = blockIdx.x, t = threadIdx.x;          // i = h, t = g
  const float* qb = qm + (size_t)bg * NN + i * 128;
  const float* kb = km + (size_t)bg * NN + (size_t)t * 128;
  __shared__ float qrow[128];
  __shared__ float wred[2];
  qrow[t] = qb[t];
  __syncthreads();
  float s = 0.f;
#pragma unroll 4
  for (int w = 0; w < 128; ++w) s += qrow[w] * kb[w];
  s *= temp[0];
  int wid = t >> 6, lane = t & 63;
  float mx = wave_max(s);
  if (lane == 0) wred[wid] = mx;
  __syncthreads();
  mx = fmaxf(wred[0], wred[1]);
  float pv = __expf(s - mx);
  __syncthreads();
  float sm = wave_sum(pv);
  if (lane == 0) wred[wid] = sm;
  __syncthreads();
  float denom = wred[0] + wred[1];
  attn[(size_t)bg * NN + i * 128 + t] = pv / denom;
}

// ---- apply1: out[bz,(c,h),v] = sum_w v1[bz,(c,h),w] * attn[bg,w,v] ----
__global__ __launch_bounds__(256) void k_apply1(const float* __restrict__ qkv,
                                                const float* __restrict__ attn,
                                                float* __restrict__ outp, int b0) {
  __shared__ float As[64][33];
  __shared__ float Bs[32][128];
  int bz = blockIdx.z, bg = b0 + bz;
  int m0 = blockIdx.x * 64;
  int t = threadIdx.x, to = t >> 4, tn = t & 15;
  const float* vb = qkv + (size_t)bz * O3N + (size_t)256 * NN;   // v1 rows: (c*128+h) x 128
  const float* ab = attn + (size_t)bg * NN;
  float acc[4][8];
#pragma unroll
  for (int i = 0; i < 4; ++i)
#pragma unroll
    for (int j = 0; j < 8; ++j) acc[i][j] = 0.f;

  for (int kk = 0; kk < 128; kk += 32) {
#pragma unroll
    for (int r = 0; r < 8; ++r) {
      int idx = r * 256 + t, m = idx >> 5, k2 = idx & 31;
      As[m][k2] = vb[(size_t)(m0 + m) * 128 + kk + k2];
    }
#pragma unroll
    for (int r = 0; r < 16; ++r) {
      int idx = r * 256 + t, k2 = idx >> 7, n = idx & 127;
      Bs[k2][n] = ab[(size_t)(kk + k2) * 128 + n];
    }
    __syncthreads();
#pragma unroll
    for (int k2 = 0; k2 < 32; ++k2) {
      float a0 = As[to * 4 + 0][k2], a1 = As[to * 4 + 1][k2];
      float a2 = As[to * 4 + 2][k2], a3 = As[to * 4 + 3][k2];
      const float4* bp = (const float4*)&Bs[k2][tn * 8];
      float4 b0v = bp[0], b1v = bp[1];
      float bv[8] = {b0v.x, b0v.y, b0v.z, b0v.w, b1v.x, b1v.y, b1v.z, b1v.w};
#pragma unroll
      for (int j = 0; j < 8; ++j) {
        acc[0][j] += a0 * bv[j]; acc[1][j] += a1 * bv[j];
        acc[2][j] += a2 * bv[j]; acc[3][j] += a3 * bv[j];
      }
    }
    __syncthreads();
  }
  float* ob = outp + (size_t)bz * CN + tn * 8;
#pragma unroll
  for (int i = 0; i < 4; ++i) {
    int row = m0 + to * 4 + i;
    float4 v0 = make_float4(acc[i][0], acc[i][1], acc[i][2], acc[i][3]);
    float4 v1 = make_float4(acc[i][4], acc[i][5], acc[i][6], acc[i][7]);
    float4* dst = (float4*)(ob + (size_t)row * 128);
    dst[0] = v0; dst[1] = v1;
  }
}

// ---- apply2: out[bz,c,g,w] = sum_h attn[bg,h,g] * v2[bz,c,h,w] ----
__global__ __launch_bounds__(256) void k_apply2(const float* __restrict__ qkv,
                                                const float* __restrict__ attn,
                                                float* __restrict__ outp, int b0) {
  __shared__ float As[64][33];
  __shared__ float Bs[32][128];
  int bz = blockIdx.z, bg = b0 + bz;
  int g0 = blockIdx.x * 64, c = blockIdx.y;
  int t = threadIdx.x, to = t >> 4, tn = t & 15;
  const float* vb = qkv + (size_t)bz * O3N + (size_t)(256 + c) * NN;
  const float* ab = attn + (size_t)bg * NN;
  float acc[4][8];
#pragma unroll
  for (int i = 0; i < 4; ++i)
#pragma unroll
    for (int j = 0; j < 8; ++j) acc[i][j] = 0.f;

  for (int kk = 0; kk < 128; kk += 32) {
#pragma unroll
    for (int r = 0; r < 8; ++r) {           // A[g][h] = attn[h][g], coalesced over g
      int idx = r * 256 + t, m = idx & 63, k2 = idx >> 6;
      As[m][k2] = ab[(size_t)(kk + k2) * 128 + g0 + m];
    }
#pragma unroll
    for (int r = 0; r < 16; ++r) {
      int idx = r * 256 + t, k2 = idx >> 7, n = idx & 127;
      Bs[k2][n] = vb[(size_t)(kk + k2) * 128 + n];
    }
    __syncthreads();
#pragma unroll
    for (int k2 = 0; k2 < 32; ++k2) {
      float a0 = As[to * 4 + 0][k2], a1 = As[to * 4 + 1][k2];
      float a2 = As[to * 4 + 2][k2], a3 = As[to * 4 + 3][k2];
      const float4* bp = (const float4*)&Bs[k2][tn * 8];
      float4 b0v = bp[0], b1v = bp[1];
      float bv[8] = {b0v.x, b0v.y, b0v.z, b0v.w, b1v.x, b1v.y, b1v.z, b1v.w};
#pragma unroll
      for (int j = 0; j < 8; ++j) {
        acc[0][j] += a0 * bv[j]; acc[1][j] += a1 * bv[j];
        acc[2][j] += a2 * bv[j]; acc[3][j] += a3 * bv[j];
      }
    }
    __syncthreads();
  }
  float* ob = outp + (size_t)bz * CN + (size_t)c * NN + tn * 8;
#pragma unroll
  for (int i = 0; i < 4; ++i) {
    int g = g0 + to * 4 + i;
    float4 v0 = make_float4(acc[i][0], acc[i][1], acc[i][2], acc[i][3]);
    float4 v1 = make_float4(acc[i][4], acc[i][5], acc[i][6], acc[i][7]);
    float4* dst = (float4*)(ob + (size_t)g * 128);
    dst[0] = v0; dst[1] = v1;
  }
}

// ---- proj (1x1 conv) + residual: dst[bg,o,n] = res[bg,o,n] + sum_c pw[o,c]*tin[bz,c,n] + pb[o] ----
__global__ __launch_bounds__(256) void k_proj_res(const float* __restrict__ tin,
                                                  const float* __restrict__ pw,
                                                  const float* __restrict__ pb,
                                                  const float* __restrict__ res,
                                                  float* __restrict__ dst, int b0) {
  __shared__ float As[64][33];
  __shared__ float Bs[32][128];
  int bz = blockIdx.z, bg = b0 + bz;
  int n0 = blockIdx.x * 128, o0 = blockIdx.y * 64;
  int t = threadIdx.x, to = t >> 4, tn = t & 15;
  const float* tb = tin + (size_t)bz * CN + n0;
  float acc[4][8];
#pragma unroll
  for (int i = 0; i < 4; ++i)
#pragma unroll
    for (int j = 0; j < 8; ++j) acc[i][j] = 0.f;

  for (int kk = 0; kk < 128; kk += 32) {
#pragma unroll
    for (int r = 0; r < 8; ++r) {
      int idx = r * 256 + t, m = idx >> 5, k2 = idx & 31;
      As[m][k2] = pw[(size_t)(o0 + m) * CC + kk + k2];
    }
#pragma unroll
    for (int r = 0; r < 16; ++r) {
      int idx = r * 256 + t, k2 = idx >> 7, n = idx & 127;
      Bs[k2][n] = tb[(size_t)(kk + k2) * NN + n];
    }
    __syncthreads();
#pragma unroll
    for (int k2 = 0; k2 < 32; ++k2) {
      float a0 = As[to * 4 + 0][k2], a1 = As[to * 4 + 1][k2];
      float a2 = As[to * 4 + 2][k2], a3 = As[to * 4 + 3][k2];
      const float4* bp = (const float4*)&Bs[k2][tn * 8];
      float4 b0v = bp[0], b1v = bp[1];
      float bv[8] = {b0v.x, b0v.y, b0v.z, b0v.w, b1v.x, b1v.y, b1v.z, b1v.w};
#pragma unroll
      for (int j = 0; j < 8; ++j) {
        acc[0][j] += a0 * bv[j]; acc[1][j] += a1 * bv[j];
        acc[2][j] += a2 * bv[j]; acc[3][j] += a3 * bv[j];
      }
    }
    __syncthreads();
  }
#pragma unroll
  for (int i = 0; i < 4; ++i) {
    int o = o0 + to * 4 + i;
    float bias = pb[o];
    size_t off = (size_t)bg * CN + (size_t)o * NN + n0 + tn * 8;
    const float4* rp = (const float4*)(res + off);
    float4 r0 = rp[0], r1 = rp[1];
    float4 v0 = make_float4(acc[i][0] + bias + r0.x, acc[i][1] + bias + r0.y,
                            acc[i][2] + bias + r0.z, acc[i][3] + bias + r0.w);
    float4 v1 = make_float4(acc[i][4] + bias + r1.x, acc[i][5] + bias + r1.y,
                            acc[i][6] + bias + r1.z, acc[i][7] + bias + r1.w);
    float4* dp = (float4*)(dst + off);
    dp[0] = v0; dp[1] = v1;
  }
}

extern "C" void kernel_launch(void* const* d_in, const int* in_sizes, int n_in,
                              void* d_out, int out_size, void* d_ws, size_t ws_size,
                              hipStream_t stream) {
  (void)in_sizes; (void)n_in; (void)out_size;
  const float* x     = (const float*)d_in[0];
  const float* lnw   = (const float*)d_in[1];
  const float* lnb   = (const float*)d_in[2];
  const float* qkvw  = (const float*)d_in[3];
  const float* qkvb  = (const float*)d_in[4];
  const float* dww   = (const float*)d_in[5];
  const float* dwb   = (const float*)d_in[6];
  const float* projw = (const float*)d_in[7];
  const float* projb = (const float*)d_in[8];
  const float* temp1 = (const float*)d_in[9];
  const float* temp2 = (const float*)d_in[10];
  float* out = (float*)d_out;
  float* ws = (float*)d_ws;

  const size_t FULLF = 2ull * 8 * O3N + 16777216ull + 5ull * 131072;   // floats, NB=8
  const size_t PBF   = 2ull * 1 * O3N + 16777216ull + 5ull * 131072;   // floats, NB=1
  int NB = (ws_size >= FULLF * 4) ? 8 : 1;
  if (ws_size < PBF * 4) return;  // cannot run safely in available scratch

  size_t convN = (size_t)NB * O3N;
  float* convbuf = ws;
  float* qkvbuf  = convbuf + convN;
  float* out1    = qkvbuf + convN;          // full (B,C,N), 64MB, persists across stages
  float* mu      = out1 + 16777216;
  float* rs      = mu + 131072;
  float* qm      = rs + 131072;
  float* km      = qm + 131072;
  float* attn    = km + 131072;
  float* tmpb    = convbuf;                 // alias: conv buffer dead after dwc

  for (int stage = 0; stage < 2; ++stage) {
    const float* src = stage ? out1 : x;
    k_stats<<<512, 256, 0, stream>>>(src, mu, rs);
    for (int b0 = 0; b0 < 8; b0 += NB) {
      k_conv_ln<<<dim3(128, 6, NB), 256, 0, stream>>>(src, mu, rs, lnw, lnb, qkvw, qkvb, convbuf, b0);
      k_dwc<<<dim3(64, 384, NB), 256, 0, stream>>>(convbuf, dww, dwb, qkvbuf);
      if (stage == 0)
        k_reduce1<<<dim3(64, NB), 256, 0, stream>>>(qkvbuf, qm, km, b0);
      else
        k_reduce2<<<dim3(64, NB), 256, 0, stream>>>(qkvbuf, qm, km, b0);
      k_norm_rows<<<NB * 128, 64, 0, stream>>>(qm, b0 * 128);
      k_norm_rows<<<NB * 128, 64, 0, stream>>>(km, b0 * 128);
      if (stage == 0)
        k_attn1<<<dim3(128, NB), 128, 0, stream>>>(qm, km, temp1, attn, b0);
      else
        k_attn2<<<dim3(128, NB), 128, 0, stream>>>(qm, km, temp2, attn, b0);
      if (stage == 0)
        k_apply1<<<dim3(256, 1, NB), 256, 0, stream>>>(qkvbuf, attn, tmpb, b0);
      else
        k_apply2<<<dim3(2, 128, NB), 256, 0, stream>>>(qkvbuf, attn, tmpb, b0);
      const float* resp = stage ? out1 : x;
      float* dstp = stage ? out : out1;
      k_proj_res<<<dim3(128, 2, NB), 256, 0, stream>>>(tmpb, projw, projb, resp, dstp, b0);
    }
  }
}

// Round 2
// 1105.909 us; speedup vs baseline: 1.8434x; 1.8434x over previous
//
#include <hip/hip_runtime.h>

// dims
static constexpr int CC = 128, NN = 16384;       // C, H*W (H=W=128)
static constexpr int O3 = 384;                   // 3*C
static constexpr long long CN  = (long long)CC * NN;   // 2097152
static constexpr long long O3N = (long long)O3 * NN;   // 6291456

__device__ __forceinline__ float wave_sum(float v) {
  for (int o = 32; o; o >>= 1) v += __shfl_xor(v, o);
  return v;
}
__device__ __forceinline__ float wave_max(float v) {
  for (int o = 32; o; o >>= 1) v = fmaxf(v, __shfl_xor(v, o));
  return v;
}

// ---- per-pixel LN stats over channels: mu, rstd (full batch) ----
__global__ __launch_bounds__(256) void k_stats(const float* __restrict__ in,
                                               float* __restrict__ mu,
                                               float* __restrict__ rs) {
  int p = blockIdx.x * 256 + threadIdx.x;          // [0, B*N)
  int b = p >> 14, n = p & (NN - 1);
  const float* base = in + (size_t)b * CN + n;
  float s1 = 0.f, s2 = 0.f;
#pragma unroll 8
  for (int c = 0; c < CC; ++c) { float v = base[(size_t)c * NN]; s1 += v; s2 += v * v; }
  float m = s1 * (1.f / CC);
  float var = s2 * (1.f / CC) - m * m;
  mu[p] = m;
  rs[p] = rsqrtf(var + 1e-5f);
}

// ---- fused LN + 1x1 conv (qkv): out[bz,o,n] = sum_c W[o,c]*ln(x[bg,c,n]) + b[o] ----
__global__ __launch_bounds__(256) void k_conv_ln(
    const float* __restrict__ x, const float* __restrict__ mu, const float* __restrict__ rs,
    const float* __restrict__ lnw, const float* __restrict__ lnb,
    const float* __restrict__ wq, const float* __restrict__ bq,
    float* __restrict__ out, int b0) {
  __shared__ float As[64][33];
  __shared__ float Bs[32][128];
  int bz = blockIdx.z, bg = b0 + bz;
  int n0 = blockIdx.x * 128, o0 = blockIdx.y * 64;
  int t = threadIdx.x, to = t >> 4, tn = t & 15;
  const float* xb  = x  + (size_t)bg * CN + n0;
  const float* mub = mu + (size_t)bg * NN + n0;
  const float* rsb = rs + (size_t)bg * NN + n0;
  float acc[4][8];
#pragma unroll
  for (int i = 0; i < 4; ++i)
#pragma unroll
    for (int j = 0; j < 8; ++j) acc[i][j] = 0.f;

  for (int kk = 0; kk < 128; kk += 32) {
#pragma unroll
    for (int r = 0; r < 8; ++r) {
      int idx = r * 256 + t, m = idx >> 5, k2 = idx & 31;
      As[m][k2] = wq[(size_t)(o0 + m) * CC + kk + k2];
    }
#pragma unroll
    for (int r = 0; r < 16; ++r) {
      int idx = r * 256 + t, k2 = idx >> 7, n = idx & 127;
      int c = kk + k2;
      float v = xb[(size_t)c * NN + n];
      Bs[k2][n] = (v - mub[n]) * rsb[n] * lnw[c] + lnb[c];
    }
    __syncthreads();
#pragma unroll
    for (int k2 = 0; k2 < 32; ++k2) {
      float a0 = As[to * 4 + 0][k2], a1 = As[to * 4 + 1][k2];
      float a2 = As[to * 4 + 2][k2], a3 = As[to * 4 + 3][k2];
      const float4* bp = (const float4*)&Bs[k2][tn * 8];
      float4 b0v = bp[0], b1v = bp[1];
      float bv[8] = {b0v.x, b0v.y, b0v.z, b0v.w, b1v.x, b1v.y, b1v.z, b1v.w};
#pragma unroll
      for (int j = 0; j < 8; ++j) {
        acc[0][j] += a0 * bv[j]; acc[1][j] += a1 * bv[j];
        acc[2][j] += a2 * bv[j]; acc[3][j] += a3 * bv[j];
      }
    }
    __syncthreads();
  }
  float* ob = out + (size_t)bz * O3N + n0 + tn * 8;
#pragma unroll
  for (int i = 0; i < 4; ++i) {
    int o = o0 + to * 4 + i;
    float bias = bq[o];
    float4 v0 = make_float4(acc[i][0] + bias, acc[i][1] + bias, acc[i][2] + bias, acc[i][3] + bias);
    float4 v1 = make_float4(acc[i][4] + bias, acc[i][5] + bias, acc[i][6] + bias, acc[i][7] + bias);
    float4* dst = (float4*)(ob + (size_t)o * NN);
    dst[0] = v0; dst[1] = v1;
  }
}

// ---- 3x3 depthwise conv, pad 1, IN PLACE (plane staged in LDS) ----
// Depthwise: each output channel depends only on its own input channel plane,
// so one block per (channel, batch) with the full plane in LDS is race-free.
__global__ __launch_bounds__(1024) void k_dwc_ip(float* __restrict__ buf,
                                                 const float* __restrict__ dww,
                                                 const float* __restrict__ dwb) {
  __shared__ float pl[128 * 128];
  int bz = blockIdx.y, o = blockIdx.x;
  float* base = buf + (size_t)bz * O3N + (size_t)o * NN;
  int t = threadIdx.x;
  float4* pl4 = (float4*)pl;
  const float4* g4 = (const float4*)base;
#pragma unroll
  for (int i = 0; i < 4; ++i) pl4[i * 1024 + t] = g4[i * 1024 + t];
  __syncthreads();
  const float* wg = dww + o * 9;
  float w00 = wg[0], w01 = wg[1], w02 = wg[2];
  float w10 = wg[3], w11 = wg[4], w12 = wg[5];
  float w20 = wg[6], w21 = wg[7], w22 = wg[8];
  float bias = dwb[o];
#pragma unroll
  for (int i = 0; i < 16; ++i) {
    int p = i * 1024 + t;
    int h = p >> 7, w = p & 127;
    float acc = bias;
    bool hu = h > 0, hd = h < 127, wl = w > 0, wr = w < 127;
    const float* rm = pl + h * 128 + w;
    if (hu) {
      const float* r = rm - 128;
      if (wl) acc += r[-1] * w00;
      acc += r[0] * w01;
      if (wr) acc += r[1] * w02;
    }
    if (wl) acc += rm[-1] * w10;
    acc += rm[0] * w11;
    if (wr) acc += rm[1] * w12;
    if (hd) {
      const float* r = rm + 128;
      if (wl) acc += r[-1] * w20;
      acc += r[0] * w21;
      if (wr) acc += r[1] * w22;
    }
    base[p] = acc;
  }
}

// ---- stage-1 reductions: q mean over h, k max over h  -> [b, c, w] ----
__global__ __launch_bounds__(256) void k_reduce1(const float* __restrict__ qkv,
                                                 float* __restrict__ qm, float* __restrict__ km,
                                                 int b0) {
  int bz = blockIdx.y;
  int idx = blockIdx.x * 256 + threadIdx.x;   // c*128 + w
  int c = idx >> 7, w = idx & 127;
  const float* base = qkv + (size_t)bz * O3N;
  const float* q = base + (size_t)c * NN + w;
  const float* k = base + (size_t)(c + 128) * NN + w;
  float s = 0.f, mx = -1e30f;
#pragma unroll 4
  for (int h = 0; h < 128; ++h) { s += q[h * 128]; mx = fmaxf(mx, k[h * 128]); }
  size_t off = (size_t)(b0 + bz) * NN + idx;
  qm[off] = s * (1.f / 128.f);
  km[off] = mx;
}

// ---- stage-2 reductions: mean over channels -> [b, h, w] ----
__global__ __launch_bounds__(256) void k_reduce2(const float* __restrict__ qkv,
                                                 float* __restrict__ qm, float* __restrict__ km,
                                                 int b0) {
  int bz = blockIdx.y;
  int n = blockIdx.x * 256 + threadIdx.x;
  const float* base = qkv + (size_t)bz * O3N + n;
  float sq = 0.f, sk = 0.f;
#pragma unroll 4
  for (int c = 0; c < 128; ++c) { sq += base[(size_t)c * NN]; sk += base[(size_t)(c + 128) * NN]; }
  size_t off = (size_t)(b0 + bz) * NN + n;
  qm[off] = sq * (1.f / 128.f);
  km[off] = sk * (1.f / 128.f);
}

// ---- l2-normalize rows of length 128 in place (both q and k buffers) ----
__global__ void k_norm2(float* __restrict__ qm, float* __restrict__ km, int row0) {
  float* buf = blockIdx.y ? km : qm;
  int r = row0 + blockIdx.x, t = threadIdx.x;   // 64 threads
  float* p = buf + (size_t)r * 128;
  float v0 = p[t], v1 = p[t + 64];
  float s = wave_sum(v0 * v0 + v1 * v1);
  float sc = 1.f / fmaxf(sqrtf(s), 1e-12f);
  p[t] = v0 * sc;
  p[t + 64] = v1 * sc;
}

// ---- attn1[b,i,j] = softmax_j( sum_c qm[b,c,i]*km[b,c,j] * temp ) ----
__global__ void k_attn1(const float* __restrict__ qm, const float* __restrict__ km,
                        const float* __restrict__ temp, float* __restrict__ attn, int b0) {
  int bg = b0 + blockIdx.y;
  int i = blockIdx.x, t = threadIdx.x;          // 128 threads, t = j
  const float* qb = qm + (size_t)bg * NN;
  const float* kb = km + (size_t)bg * NN;
  __shared__ float qcol[128];
  __shared__ float wred[2];
  qcol[t] = qb[t * 128 + i];
  __syncthreads();
  float s = 0.f;
#pragma unroll 4
  for (int k = 0; k < 128; ++k) s += qcol[k] * kb[k * 128 + t];
  s *= temp[0];
  int wid = t >> 6, lane = t & 63;
  float mx = wave_max(s);
  if (lane == 0) wred[wid] = mx;
  __syncthreads();
  mx = fmaxf(wred[0], wred[1]);
  float pv = __expf(s - mx);
  __syncthreads();
  float sm = wave_sum(pv);
  if (lane == 0) wred[wid] = sm;
  __syncthreads();
  float denom = wred[0] + wred[1];
  attn[(size_t)bg * NN + i * 128 + t] = pv / denom;
}

// ---- attn2[b,h,g] = softmax_g( sum_w qm[b,h,w]*km[b,g,w] * temp ) ----
__global__ void k_attn2(const float* __restrict__ qm, const float* __restrict__ km,
                        const float* __restrict__ temp, float* __restrict__ attn, int b0) {
  int bg = b0 + blockIdx.y;
  int i = blockIdx.x, t = threadIdx.x;          // i = h, t = g
  const float* qb = qm + (size_t)bg * NN + i * 128;
  const float* kb = km + (size_t)bg * NN + (size_t)t * 128;
  __shared__ float qrow[128];
  __shared__ float wred[2];
  qrow[t] = qb[t];
  __syncthreads();
  float s = 0.f;
#pragma unroll 4
  for (int w = 0; w < 128; ++w) s += qrow[w] * kb[w];
  s *= temp[0];
  int wid = t >> 6, lane = t & 63;
  float mx = wave_max(s);
  if (lane == 0) wred[wid] = mx;
  __syncthreads();
  mx = fmaxf(wred[0], wred[1]);
  float pv = __expf(s - mx);
  __syncthreads();
  float sm = wave_sum(pv);
  if (lane == 0) wred[wid] = sm;
  __syncthreads();
  float denom = wred[0] + wred[1];
  attn[(size_t)bg * NN + i * 128 + t] = pv / denom;
}

// ---- apply1: tmp[bz,(c,h),v] = sum_w v1[bz,(c,h),w] * attn[bg,w,v] ----
// tmp aliases the (dead) q-region of qkv buffer: batch stride O3N, first CN floats.
__global__ __launch_bounds__(256) void k_apply1(const float* __restrict__ qkv,
                                                const float* __restrict__ attn,
                                                float* __restrict__ outp, int b0) {
  __shared__ float As[64][33];
  __shared__ float Bs[32][128];
  int bz = blockIdx.z, bg = b0 + bz;
  int m0 = blockIdx.x * 64;
  int t = threadIdx.x, to = t >> 4, tn = t & 15;
  const float* vb = qkv + (size_t)bz * O3N + (size_t)256 * NN;   // v1 rows: (c*128+h) x 128
  const float* ab = attn + (size_t)bg * NN;
  float acc[4][8];
#pragma unroll
  for (int i = 0; i < 4; ++i)
#pragma unroll
    for (int j = 0; j < 8; ++j) acc[i][j] = 0.f;

  for (int kk = 0; kk < 128; kk += 32) {
#pragma unroll
    for (int r = 0; r < 8; ++r) {
      int idx = r * 256 + t, m = idx >> 5, k2 = idx & 31;
      As[m][k2] = vb[(size_t)(m0 + m) * 128 + kk + k2];
    }
#pragma unroll
    for (int r = 0; r < 16; ++r) {
      int idx = r * 256 + t, k2 = idx >> 7, n = idx & 127;
      Bs[k2][n] = ab[(size_t)(kk + k2) * 128 + n];
    }
    __syncthreads();
#pragma unroll
    for (int k2 = 0; k2 < 32; ++k2) {
      float a0 = As[to * 4 + 0][k2], a1 = As[to * 4 + 1][k2];
      float a2 = As[to * 4 + 2][k2], a3 = As[to * 4 + 3][k2];
      const float4* bp = (const float4*)&Bs[k2][tn * 8];
      float4 b0v = bp[0], b1v = bp[1];
      float bv[8] = {b0v.x, b0v.y, b0v.z, b0v.w, b1v.x, b1v.y, b1v.z, b1v.w};
#pragma unroll
      for (int j = 0; j < 8; ++j) {
        acc[0][j] += a0 * bv[j]; acc[1][j] += a1 * bv[j];
        acc[2][j] += a2 * bv[j]; acc[3][j] += a3 * bv[j];
      }
    }
    __syncthreads();
  }
  float* ob = outp + (size_t)bz * O3N + tn * 8;
#pragma unroll
  for (int i = 0; i < 4; ++i) {
    int row = m0 + to * 4 + i;
    float4 v0 = make_float4(acc[i][0], acc[i][1], acc[i][2], acc[i][3]);
    float4 v1 = make_float4(acc[i][4], acc[i][5], acc[i][6], acc[i][7]);
    float4* dst = (float4*)(ob + (size_t)row * 128);
    dst[0] = v0; dst[1] = v1;
  }
}

// ---- apply2: tmp[bz,c,g,w] = sum_h attn[bg,h,g] * v2[bz,c,h,w] ----
__global__ __launch_bounds__(256) void k_apply2(const float* __restrict__ qkv,
                                                const float* __restrict__ attn,
                                                float* __restrict__ outp, int b0) {
  __shared__ float As[64][33];
  __shared__ float Bs[32][128];
  int bz = blockIdx.z, bg = b0 + bz;
  int g0 = blockIdx.x * 64, c = blockIdx.y;
  int t = threadIdx.x, to = t >> 4, tn = t & 15;
  const float* vb = qkv + (size_t)bz * O3N + (size_t)(256 + c) * NN;
  const float* ab = attn + (size_t)bg * NN;
  float acc[4][8];
#pragma unroll
  for (int i = 0; i < 4; ++i)
#pragma unroll
    for (int j = 0; j < 8; ++j) acc[i][j] = 0.f;

  for (int kk = 0; kk < 128; kk += 32) {
#pragma unroll
    for (int r = 0; r < 8; ++r) {           // A[g][h] = attn[h][g], coalesced over g
      int idx = r * 256 + t, m = idx & 63, k2 = idx >> 6;
      As[m][k2] = ab[(size_t)(kk + k2) * 128 + g0 + m];
    }
#pragma unroll
    for (int r = 0; r < 16; ++r) {
      int idx = r * 256 + t, k2 = idx >> 7, n = idx & 127;
      Bs[k2][n] = vb[(size_t)(kk + k2) * 128 + n];
    }
    __syncthreads();
#pragma unroll
    for (int k2 = 0; k2 < 32; ++k2) {
      float a0 = As[to * 4 + 0][k2], a1 = As[to * 4 + 1][k2];
      float a2 = As[to * 4 + 2][k2], a3 = As[to * 4 + 3][k2];
      const float4* bp = (const float4*)&Bs[k2][tn * 8];
      float4 b0v = bp[0], b1v = bp[1];
      float bv[8] = {b0v.x, b0v.y, b0v.z, b0v.w, b1v.x, b1v.y, b1v.z, b1v.w};
#pragma unroll
      for (int j = 0; j < 8; ++j) {
        acc[0][j] += a0 * bv[j]; acc[1][j] += a1 * bv[j];
        acc[2][j] += a2 * bv[j]; acc[3][j] += a3 * bv[j];
      }
    }
    __syncthreads();
  }
  float* ob = outp + (size_t)bz * O3N + (size_t)c * NN + tn * 8;
#pragma unroll
  for (int i = 0; i < 4; ++i) {
    int g = g0 + to * 4 + i;
    float4 v0 = make_float4(acc[i][0], acc[i][1], acc[i][2], acc[i][3]);
    float4 v1 = make_float4(acc[i][4], acc[i][5], acc[i][6], acc[i][7]);
    float4* dst = (float4*)(ob + (size_t)g * 128);
    dst[0] = v0; dst[1] = v1;
  }
}

// ---- proj (1x1 conv) + residual: dst[bg,o,n] = res[bg,o,n] + sum_c pw[o,c]*tin[bz,c,n] + pb[o] ----
// tin has batch stride O3N (aliases q-region of qkv buffer)
__global__ __launch_bounds__(256) void k_proj_res(const float* __restrict__ tin,
                                                  const float* __restrict__ pw,
                                                  const float* __restrict__ pb,
                                                  const float* __restrict__ res,
                                                  float* __restrict__ dst, int b0) {
  __shared__ float As[64][33];
  __shared__ float Bs[32][128];
  int bz = blockIdx.z, bg = b0 + bz;
  int n0 = blockIdx.x * 128, o0 = blockIdx.y * 64;
  int t = threadIdx.x, to = t >> 4, tn = t & 15;
  const float* tb = tin + (size_t)bz * O3N + n0;
  float acc[4][8];
#pragma unroll
  for (int i = 0; i < 4; ++i)
#pragma unroll
    for (int j = 0; j < 8; ++j) acc[i][j] = 0.f;

  for (int kk = 0; kk < 128; kk += 32) {
#pragma unroll
    for (int r = 0; r < 8; ++r) {
      int idx = r * 256 + t, m = idx >> 5, k2 = idx & 31;
      As[m][k2] = pw[(size_t)(o0 + m) * CC + kk + k2];
    }
#pragma unroll
    for (int r = 0; r < 16; ++r) {
      int idx = r * 256 + t, k2 = idx >> 7, n = idx & 127;
      Bs[k2][n] = tb[(size_t)(kk + k2) * NN + n];
    }
    __syncthreads();
#pragma unroll
    for (int k2 = 0; k2 < 32; ++k2) {
      float a0 = As[to * 4 + 0][k2], a1 = As[to * 4 + 1][k2];
      float a2 = As[to * 4 + 2][k2], a3 = As[to * 4 + 3][k2];
      const float4* bp = (const float4*)&Bs[k2][tn * 8];
      float4 b0v = bp[0], b1v = bp[1];
      float bv[8] = {b0v.x, b0v.y, b0v.z, b0v.w, b1v.x, b1v.y, b1v.z, b1v.w};
#pragma unroll
      for (int j = 0; j < 8; ++j) {
        acc[0][j] += a0 * bv[j]; acc[1][j] += a1 * bv[j];
        acc[2][j] += a2 * bv[j]; acc[3][j] += a3 * bv[j];
      }
    }
    __syncthreads();
  }
#pragma unroll
  for (int i = 0; i < 4; ++i) {
    int o = o0 + to * 4 + i;
    float bias = pb[o];
    size_t off = (size_t)bg * CN + (size_t)o * NN + n0 + tn * 8;
    const float4* rp = (const float4*)(res + off);
    float4 r0 = rp[0], r1 = rp[1];
    float4 v0 = make_float4(acc[i][0] + bias + r0.x, acc[i][1] + bias + r0.y,
                            acc[i][2] + bias + r0.z, acc[i][3] + bias + r0.w);
    float4 v1 = make_float4(acc[i][4] + bias + r1.x, acc[i][5] + bias + r1.y,
                            acc[i][6] + bias + r1.z, acc[i][7] + bias + r1.w);
    float4* dp = (float4*)(dst + off);
    dp[0] = v0; dp[1] = v1;
  }
}

extern "C" void kernel_launch(void* const* d_in, const int* in_sizes, int n_in,
                              void* d_out, int out_size, void* d_ws, size_t ws_size,
                              hipStream_t stream) {
  (void)in_sizes; (void)n_in; (void)out_size;
  const float* x     = (const float*)d_in[0];
  const float* lnw   = (const float*)d_in[1];
  const float* lnb   = (const float*)d_in[2];
  const float* qkvw  = (const float*)d_in[3];
  const float* qkvb  = (const float*)d_in[4];
  const float* dww   = (const float*)d_in[5];
  const float* dwb   = (const float*)d_in[6];
  const float* projw = (const float*)d_in[7];
  const float* projb = (const float*)d_in[8];
  const float* temp1 = (const float*)d_in[9];
  const float* temp2 = (const float*)d_in[10];
  float* out = (float*)d_out;
  float* ws = (float*)d_ws;

  const size_t SMALLF = 4ull * 131072;                 // mu, rs, qm, km  (attn reuses its own slot)
  auto needBytes = [&](int nb) { return ((size_t)nb * O3N + SMALLF + 131072) * 4; };
  int NB = 8;
  while (NB > 1 && ws_size < needBytes(NB)) NB >>= 1;
  if (ws_size < needBytes(1)) return;

  float* convbuf = ws;                       // NB * O3N; holds conv, then qkv (in-place dwc),
                                             // then q-region is reused as apply-output tmp
  float* mu   = convbuf + (size_t)NB * O3N;
  float* rs   = mu + 131072;
  float* qm   = rs + 131072;
  float* km   = qm + 131072;
  float* attn = km + 131072;
  // out1 lives in d_out (stage-2 proj reads res and writes dst at identical offsets)

  for (int stage = 0; stage < 2; ++stage) {
    const float* src = stage ? out : x;
    k_stats<<<512, 256, 0, stream>>>(src, mu, rs);
    for (int b0 = 0; b0 < 8; b0 += NB) {
      k_conv_ln<<<dim3(128, 6, NB), 256, 0, stream>>>(src, mu, rs, lnw, lnb, qkvw, qkvb, convbuf, b0);
      k_dwc_ip<<<dim3(384, NB), 1024, 0, stream>>>(convbuf, dww, dwb);
      if (stage == 0)
        k_reduce1<<<dim3(64, NB), 256, 0, stream>>>(convbuf, qm, km, b0);
      else
        k_reduce2<<<dim3(64, NB), 256, 0, stream>>>(convbuf, qm, km, b0);
      k_norm2<<<dim3(NB * 128, 2), 64, 0, stream>>>(qm, km, b0 * 128);
      if (stage == 0)
        k_attn1<<<dim3(128, NB), 128, 0, stream>>>(qm, km, temp1, attn, b0);
      else
        k_attn2<<<dim3(128, NB), 128, 0, stream>>>(qm, km, temp2, attn, b0);
      if (stage == 0)
        k_apply1<<<dim3(256, 1, NB), 256, 0, stream>>>(convbuf, attn, convbuf, b0);
      else
        k_apply2<<<dim3(2, 128, NB), 256, 0, stream>>>(convbuf, attn, convbuf, b0);
      const float* resp = stage ? out : x;
      k_proj_res<<<dim3(128, 2, NB), 256, 0, stream>>>(convbuf, projw, projb, resp, out, b0);
    }
  }
}

// Round 3
// 569.408 us; speedup vs baseline: 3.5803x; 1.9422x over previous
//
#include <hip/hip_runtime.h>

typedef __attribute__((ext_vector_type(8))) short bf16x8;
typedef __attribute__((ext_vector_type(4))) float f32x4;

// dims
static constexpr int CC = 128, NN = 16384;       // C, H*W (H=W=128)
static constexpr int O3 = 384;                   // 3*C
static constexpr long long CN  = (long long)CC * NN;   // 2097152
static constexpr long long O3N = (long long)O3 * NN;   // 6291456

__device__ __forceinline__ float wave_sum(float v) {
  for (int o = 32; o; o >>= 1) v += __shfl_xor(v, o);
  return v;
}
__device__ __forceinline__ float wave_max(float v) {
  for (int o = 32; o; o >>= 1) v = fmaxf(v, __shfl_xor(v, o));
  return v;
}
__device__ __forceinline__ unsigned short f2bf(float f) {
  unsigned u = __float_as_uint(f);
  u += 0x7FFF + ((u >> 16) & 1);            // RNE
  return (unsigned short)(u >> 16);
}
__device__ __forceinline__ float bf2f(unsigned short h) {
  return __uint_as_float((unsigned)h << 16);
}

// ---- prep: A' = bf16(W*lnw), S[o] = sum(A'), bias2[o] = bq + sum(W*lnb); proj W -> bf16 ----
__global__ __launch_bounds__(64) void k_prep(const float* __restrict__ qkvw,
                                             const float* __restrict__ qkvb,
                                             const float* __restrict__ lnw,
                                             const float* __restrict__ lnb,
                                             const float* __restrict__ projw,
                                             unsigned short* __restrict__ Aq,
                                             unsigned short* __restrict__ Ap,
                                             float* __restrict__ Svec,
                                             float* __restrict__ bias2) {
  int o = blockIdx.x, t = threadIdx.x;
  if (o < O3) {
    float w0 = qkvw[o * 128 + t], w1 = qkvw[o * 128 + t + 64];
    unsigned short h0 = f2bf(w0 * lnw[t]), h1 = f2bf(w1 * lnw[t + 64]);
    Aq[o * 128 + t] = h0; Aq[o * 128 + t + 64] = h1;
    float s = wave_sum(bf2f(h0) + bf2f(h1));
    float bs = wave_sum(w0 * lnb[t] + w1 * lnb[t + 64]);
    if (t == 0) { Svec[o] = s; bias2[o] = qkvb[o] + bs; }
  } else {
    int r = o - O3;
    Ap[r * 128 + t] = f2bf(projw[r * 128 + t]);
    Ap[r * 128 + t + 64] = f2bf(projw[r * 128 + t + 64]);
  }
}

// ---- per-pixel LN stats over channels: mu, rstd (full batch) ----
__global__ __launch_bounds__(256) void k_stats(const float* __restrict__ in,
                                               float* __restrict__ mu,
                                               float* __restrict__ rs) {
  int p = blockIdx.x * 256 + threadIdx.x;          // [0, B*N)
  int b = p >> 14, n = p & (NN - 1);
  const float* base = in + (size_t)b * CN + n;
  float s1 = 0.f, s2 = 0.f;
#pragma unroll 8
  for (int c = 0; c < CC; ++c) { float v = base[(size_t)c * NN]; s1 += v; s2 += v * v; }
  float m = s1 * (1.f / CC);
  float var = s2 * (1.f / CC) - m * m;
  mu[p] = m;
  rs[p] = rsqrtf(var + 1e-5f);
}

// ---- MFMA qkv GEMM with folded LN epilogue ----
// out[bz,o,n] = rs[n]*(sum_c A'[o,c]*x[c,n] - mu[n]*S[o]) + bias2[o]
// Block: 256 thr / 4 waves; tile M=384 (full) x N=64. Wave w: rows [96w, 96w+96).
__global__ __launch_bounds__(256) void k_qkv_mfma(
    const float* __restrict__ x, const float* __restrict__ mu, const float* __restrict__ rs,
    const unsigned short* __restrict__ Aq, const float* __restrict__ Svec,
    const float* __restrict__ bias2, float* __restrict__ out, int b0) {
  __shared__ unsigned short Bs[64 * 136];          // [n][c] transposed, stride 136 (16B-aligned rows)
  __shared__ unsigned short As[384 * 40];          // [o][cc] per k-step, stride 40
  int bz = blockIdx.z, bg = b0 + bz;
  int n0 = blockIdx.x * 64;
  int t = threadIdx.x, w = t >> 6, l = t & 63;
  int lr = l & 15, lg = l >> 4;
  const float* xb = x + (size_t)bg * CN + n0;

  // stage B: all K=128 x N=64, fp32 -> bf16, transposed to [n][c]
  {
    int cg = t >> 4, nl = t & 15;
#pragma unroll
    for (int r = 0; r < 8; ++r) {
      int c = r * 16 + cg;
      const float* src = xb + (size_t)c * NN + nl;
#pragma unroll
      for (int q = 0; q < 4; ++q)
        Bs[(nl + q * 16) * 136 + c] = f2bf(src[q * 16]);
    }
  }

  f32x4 acc[6][4];
#pragma unroll
  for (int i = 0; i < 6; ++i)
#pragma unroll
    for (int j = 0; j < 4; ++j) acc[i][j] = (f32x4){0.f, 0.f, 0.f, 0.f};

  const unsigned int* Asrc = (const unsigned int*)Aq;
  unsigned int* Adst = (unsigned int*)As;
  for (int ks = 0; ks < 4; ++ks) {
    __syncthreads();                      // B done (ks=0) / prior reads done
#pragma unroll
    for (int r = 0; r < 24; ++r) {        // stage A: 384 x 32 bf16 = 6144 u32
      int idx = r * 256 + t;
      int o = idx >> 4, cp = idx & 15;
      Adst[o * 20 + cp] = Asrc[(size_t)o * 64 + ks * 16 + cp];
    }
    __syncthreads();
    bf16x8 bfr[4];
#pragma unroll
    for (int j = 0; j < 4; ++j)
      bfr[j] = *(const bf16x8*)&Bs[(16 * j + lr) * 136 + ks * 32 + lg * 8];
#pragma unroll
    for (int i = 0; i < 6; ++i) {
      bf16x8 afr = *(const bf16x8*)&As[(96 * w + 16 * i + lr) * 40 + lg * 8];
#pragma unroll
      for (int j = 0; j < 4; ++j)
        acc[i][j] = __builtin_amdgcn_mfma_f32_16x16x32_bf16(afr, bfr[j], acc[i][j], 0, 0, 0);
    }
  }

  float rsv[4], muv[4];
#pragma unroll
  for (int j = 0; j < 4; ++j) {
    int n = n0 + 16 * j + lr;
    rsv[j] = rs[(size_t)bg * NN + n];
    muv[j] = mu[(size_t)bg * NN + n];
  }
#pragma unroll
  for (int i = 0; i < 6; ++i) {
    int ob = 96 * w + 16 * i + lg * 4;
    float sv[4], bv[4];
#pragma unroll
    for (int r2 = 0; r2 < 4; ++r2) { sv[r2] = Svec[ob + r2]; bv[r2] = bias2[ob + r2]; }
#pragma unroll
    for (int j = 0; j < 4; ++j) {
      int n = n0 + 16 * j + lr;
      float* op = out + (size_t)bz * O3N + n;
#pragma unroll
      for (int r2 = 0; r2 < 4; ++r2)
        op[(size_t)(ob + r2) * NN] = rsv[j] * (acc[i][j][r2] - muv[j] * sv[r2]) + bv[r2];
    }
  }
}

// ---- MFMA proj + residual: dst[bg,o,n] = res + sum_c Ap[o,c]*tin[c,n] + pb[o] ----
// Block: 256 thr / 4 waves; tile M=128 x N=64. Wave w: rows [32w, 32w+32).
__global__ __launch_bounds__(256) void k_proj_mfma(
    const float* __restrict__ tin, const unsigned short* __restrict__ Ap,
    const float* __restrict__ pb, const float* __restrict__ res,
    float* __restrict__ dst, int b0) {
  __shared__ unsigned short As2[128 * 136];        // [o][c] full K, stride 136
  __shared__ unsigned short Bs[64 * 136];          // [n][c]
  int bz = blockIdx.z, bg = b0 + bz;
  int n0 = blockIdx.x * 64;
  int t = threadIdx.x, w = t >> 6, l = t & 63;
  int lr = l & 15, lg = l >> 4;
  const float* vb = tin + (size_t)bz * O3N + n0;

  // stage A whole (128x128 bf16 = 8192 u32)
  {
    const unsigned int* Asrc = (const unsigned int*)Ap;
    unsigned int* Adst = (unsigned int*)As2;
#pragma unroll
    for (int r = 0; r < 32; ++r) {
      int idx = r * 256 + t;
      int o = idx >> 6, cp = idx & 63;
      Adst[o * 68 + cp] = Asrc[o * 64 + cp];
    }
  }
  // stage B transposed
  {
    int cg = t >> 4, nl = t & 15;
#pragma unroll
    for (int r = 0; r < 8; ++r) {
      int c = r * 16 + cg;
      const float* src = vb + (size_t)c * NN + nl;
#pragma unroll
      for (int q = 0; q < 4; ++q)
        Bs[(nl + q * 16) * 136 + c] = f2bf(src[q * 16]);
    }
  }
  __syncthreads();

  f32x4 acc[2][4];
#pragma unroll
  for (int i = 0; i < 2; ++i)
#pragma unroll
    for (int j = 0; j < 4; ++j) acc[i][j] = (f32x4){0.f, 0.f, 0.f, 0.f};

#pragma unroll
  for (int ks = 0; ks < 4; ++ks) {
    bf16x8 bfr[4];
#pragma unroll
    for (int j = 0; j < 4; ++j)
      bfr[j] = *(const bf16x8*)&Bs[(16 * j + lr) * 136 + ks * 32 + lg * 8];
#pragma unroll
    for (int i = 0; i < 2; ++i) {
      bf16x8 afr = *(const bf16x8*)&As2[(32 * w + 16 * i + lr) * 136 + ks * 32 + lg * 8];
#pragma unroll
      for (int j = 0; j < 4; ++j)
        acc[i][j] = __builtin_amdgcn_mfma_f32_16x16x32_bf16(afr, bfr[j], acc[i][j], 0, 0, 0);
    }
  }

#pragma unroll
  for (int i = 0; i < 2; ++i) {
    int ob = 32 * w + 16 * i + lg * 4;
    float bv[4];
#pragma unroll
    for (int r2 = 0; r2 < 4; ++r2) bv[r2] = pb[ob + r2];
#pragma unroll
    for (int j = 0; j < 4; ++j) {
      int n = n0 + 16 * j + lr;
#pragma unroll
      for (int r2 = 0; r2 < 4; ++r2) {
        size_t off = (size_t)bg * CN + (size_t)(ob + r2) * NN + n;
        dst[off] = acc[i][j][r2] + bv[r2] + res[off];
      }
    }
  }
}

// ---- 3x3 depthwise conv, pad 1, IN PLACE (plane staged in LDS) ----
__global__ __launch_bounds__(1024) void k_dwc_ip(float* __restrict__ buf,
                                                 const float* __restrict__ dww,
                                                 const float* __restrict__ dwb) {
  __shared__ float pl[128 * 128];
  int bz = blockIdx.y, o = blockIdx.x;
  float* base = buf + (size_t)bz * O3N + (size_t)o * NN;
  int t = threadIdx.x;
  float4* pl4 = (float4*)pl;
  const float4* g4 = (const float4*)base;
#pragma unroll
  for (int i = 0; i < 4; ++i) pl4[i * 1024 + t] = g4[i * 1024 + t];
  __syncthreads();
  const float* wg = dww + o * 9;
  float w00 = wg[0], w01 = wg[1], w02 = wg[2];
  float w10 = wg[3], w11 = wg[4], w12 = wg[5];
  float w20 = wg[6], w21 = wg[7], w22 = wg[8];
  float bias = dwb[o];
#pragma unroll
  for (int i = 0; i < 16; ++i) {
    int p = i * 1024 + t;
    int h = p >> 7, w = p & 127;
    float acc = bias;
    bool hu = h > 0, hd = h < 127, wl = w > 0, wr = w < 127;
    const float* rm = pl + h * 128 + w;
    if (hu) {
      const float* r = rm - 128;
      if (wl) acc += r[-1] * w00;
      acc += r[0] * w01;
      if (wr) acc += r[1] * w02;
    }
    if (wl) acc += rm[-1] * w10;
    acc += rm[0] * w11;
    if (wr) acc += rm[1] * w12;
    if (hd) {
      const float* r = rm + 128;
      if (wl) acc += r[-1] * w20;
      acc += r[0] * w21;
      if (wr) acc += r[1] * w22;
    }
    base[p] = acc;
  }
}

// ---- stage-1 reductions: q mean over h, k max over h  -> [b, c, w] ----
__global__ __launch_bounds__(256) void k_reduce1(const float* __restrict__ qkv,
                                                 float* __restrict__ qm, float* __restrict__ km,
                                                 int b0) {
  int bz = blockIdx.y;
  int idx = blockIdx.x * 256 + threadIdx.x;   // c*128 + w
  int c = idx >> 7, w = idx & 127;
  const float* base = qkv + (size_t)bz * O3N;
  const float* q = base + (size_t)c * NN + w;
  const float* k = base + (size_t)(c + 128) * NN + w;
  float s = 0.f, mx = -1e30f;
#pragma unroll 4
  for (int h = 0; h < 128; ++h) { s += q[h * 128]; mx = fmaxf(mx, k[h * 128]); }
  size_t off = (size_t)(b0 + bz) * NN + idx;
  qm[off] = s * (1.f / 128.f);
  km[off] = mx;
}

// ---- stage-2 reductions: mean over channels -> [b, h, w] ----
__global__ __launch_bounds__(256) void k_reduce2(const float* __restrict__ qkv,
                                                 float* __restrict__ qm, float* __restrict__ km,
                                                 int b0) {
  int bz = blockIdx.y;
  int n = blockIdx.x * 256 + threadIdx.x;
  const float* base = qkv + (size_t)bz * O3N + n;
  float sq = 0.f, sk = 0.f;
#pragma unroll 4
  for (int c = 0; c < 128; ++c) { sq += base[(size_t)c * NN]; sk += base[(size_t)(c + 128) * NN]; }
  size_t off = (size_t)(b0 + bz) * NN + n;
  qm[off] = sq * (1.f / 128.f);
  km[off] = sk * (1.f / 128.f);
}

// ---- l2-normalize rows of length 128 in place (both q and k buffers) ----
__global__ void k_norm2(float* __restrict__ qm, float* __restrict__ km, int row0) {
  float* buf = blockIdx.y ? km : qm;
  int r = row0 + blockIdx.x, t = threadIdx.x;   // 64 threads
  float* p = buf + (size_t)r * 128;
  float v0 = p[t], v1 = p[t + 64];
  float s = wave_sum(v0 * v0 + v1 * v1);
  float sc = 1.f / fmaxf(sqrtf(s), 1e-12f);
  p[t] = v0 * sc;
  p[t + 64] = v1 * sc;
}

// ---- attn1[b,i,j] = softmax_j( sum_c qm[b,c,i]*km[b,c,j] * temp ) ----
__global__ void k_attn1(const float* __restrict__ qm, const float* __restrict__ km,
                        const float* __restrict__ temp, float* __restrict__ attn, int b0) {
  int bg = b0 + blockIdx.y;
  int i = blockIdx.x, t = threadIdx.x;          // 128 threads, t = j
  const float* qb = qm + (size_t)bg * NN;
  const float* kb = km + (size_t)bg * NN;
  __shared__ float qcol[128];
  __shared__ float wred[2];
  qcol[t] = qb[t * 128 + i];
  __syncthreads();
  float s = 0.f;
#pragma unroll 4
  for (int k = 0; k < 128; ++k) s += qcol[k] * kb[k * 128 + t];
  s *= temp[0];
  int wid = t >> 6, lane = t & 63;
  float mx = wave_max(s);
  if (lane == 0) wred[wid] = mx;
  __syncthreads();
  mx = fmaxf(wred[0], wred[1]);
  float pv = __expf(s - mx);
  __syncthreads();
  float sm = wave_sum(pv);
  if (lane == 0) wred[wid] = sm;
  __syncthreads();
  float denom = wred[0] + wred[1];
  attn[(size_t)bg * NN + i * 128 + t] = pv / denom;
}

// ---- attn2[b,h,g] = softmax_g( sum_w qm[b,h,w]*km[b,g,w] * temp ) ----
__global__ void k_attn2(const float* __restrict__ qm, const float* __restrict__ km,
                        const float* __restrict__ temp, float* __restrict__ attn, int b0) {
  int bg = b0 + blockIdx.y;
  int i = blockIdx.x, t = threadIdx.x;          // i = h, t = g
  const float* qb = qm + (size_t)bg * NN + i * 128;
  const float* kb = km + (size_t)bg * NN + (size_t)t * 128;
  __shared__ float qrow[128];
  __shared__ float wred[2];
  qrow[t] = qb[t];
  __syncthreads();
  float s = 0.f;
#pragma unroll 4
  for (int w = 0; w < 128; ++w) s += qrow[w] * kb[w];
  s *= temp[0];
  int wid = t >> 6, lane = t & 63;
  float mx = wave_max(s);
  if (lane == 0) wred[wid] = mx;
  __syncthreads();
  mx = fmaxf(wred[0], wred[1]);
  float pv = __expf(s - mx);
  __syncthreads();
  float sm = wave_sum(pv);
  if (lane == 0) wred[wid] = sm;
  __syncthreads();
  float denom = wred[0] + wred[1];
  attn[(size_t)bg * NN + i * 128 + t] = pv / denom;
}

// ---- apply1: tmp[bz,(c,h),v] = sum_w v1[bz,(c,h),w] * attn[bg,w,v] ----
__global__ __launch_bounds__(256) void k_apply1(const float* __restrict__ qkv,
                                                const float* __restrict__ attn,
                                                float* __restrict__ outp, int b0) {
  __shared__ float As[64][33];
  __shared__ float Bs[32][128];
  int bz = blockIdx.z, bg = b0 + bz;
  int m0 = blockIdx.x * 64;
  int t = threadIdx.x, to = t >> 4, tn = t & 15;
  const float* vb = qkv + (size_t)bz * O3N + (size_t)256 * NN;   // v1 rows: (c*128+h) x 128
  const float* ab = attn + (size_t)bg * NN;
  float acc[4][8];
#pragma unroll
  for (int i = 0; i < 4; ++i)
#pragma unroll
    for (int j = 0; j < 8; ++j) acc[i][j] = 0.f;

  for (int kk = 0; kk < 128; kk += 32) {
#pragma unroll
    for (int r = 0; r < 8; ++r) {
      int idx = r * 256 + t, m = idx >> 5, k2 = idx & 31;
      As[m][k2] = vb[(size_t)(m0 + m) * 128 + kk + k2];
    }
#pragma unroll
    for (int r = 0; r < 16; ++r) {
      int idx = r * 256 + t, k2 = idx >> 7, n = idx & 127;
      Bs[k2][n] = ab[(size_t)(kk + k2) * 128 + n];
    }
    __syncthreads();
#pragma unroll
    for (int k2 = 0; k2 < 32; ++k2) {
      float a0 = As[to * 4 + 0][k2], a1 = As[to * 4 + 1][k2];
      float a2 = As[to * 4 + 2][k2], a3 = As[to * 4 + 3][k2];
      const float4* bp = (const float4*)&Bs[k2][tn * 8];
      float4 b0v = bp[0], b1v = bp[1];
      float bv[8] = {b0v.x, b0v.y, b0v.z, b0v.w, b1v.x, b1v.y, b1v.z, b1v.w};
#pragma unroll
      for (int j = 0; j < 8; ++j) {
        acc[0][j] += a0 * bv[j]; acc[1][j] += a1 * bv[j];
        acc[2][j] += a2 * bv[j]; acc[3][j] += a3 * bv[j];
      }
    }
    __syncthreads();
  }
  float* ob = outp + (size_t)bz * O3N + tn * 8;
#pragma unroll
  for (int i = 0; i < 4; ++i) {
    int row = m0 + to * 4 + i;
    float4 v0 = make_float4(acc[i][0], acc[i][1], acc[i][2], acc[i][3]);
    float4 v1 = make_float4(acc[i][4], acc[i][5], acc[i][6], acc[i][7]);
    float4* dst = (float4*)(ob + (size_t)row * 128);
    dst[0] = v0; dst[1] = v1;
  }
}

// ---- apply2: tmp[bz,c,g,w] = sum_h attn[bg,h,g] * v2[bz,c,h,w] ----
__global__ __launch_bounds__(256) void k_apply2(const float* __restrict__ qkv,
                                                const float* __restrict__ attn,
                                                float* __restrict__ outp, int b0) {
  __shared__ float As[64][33];
  __shared__ float Bs[32][128];
  int bz = blockIdx.z, bg = b0 + bz;
  int g0 = blockIdx.x * 64, c = blockIdx.y;
  int t = threadIdx.x, to = t >> 4, tn = t & 15;
  const float* vb = qkv + (size_t)bz * O3N + (size_t)(256 + c) * NN;
  const float* ab = attn + (size_t)bg * NN;
  float acc[4][8];
#pragma unroll
  for (int i = 0; i < 4; ++i)
#pragma unroll
    for (int j = 0; j < 8; ++j) acc[i][j] = 0.f;

  for (int kk = 0; kk < 128; kk += 32) {
#pragma unroll
    for (int r = 0; r < 8; ++r) {           // A[g][h] = attn[h][g], coalesced over g
      int idx = r * 256 + t, m = idx & 63, k2 = idx >> 6;
      As[m][k2] = ab[(size_t)(kk + k2) * 128 + g0 + m];
    }
#pragma unroll
    for (int r = 0; r < 16; ++r) {
      int idx = r * 256 + t, k2 = idx >> 7, n = idx & 127;
      Bs[k2][n] = vb[(size_t)(kk + k2) * 128 + n];
    }
    __syncthreads();
#pragma unroll
    for (int k2 = 0; k2 < 32; ++k2) {
      float a0 = As[to * 4 + 0][k2], a1 = As[to * 4 + 1][k2];
      float a2 = As[to * 4 + 2][k2], a3 = As[to * 4 + 3][k2];
      const float4* bp = (const float4*)&Bs[k2][tn * 8];
      float4 b0v = bp[0], b1v = bp[1];
      float bv[8] = {b0v.x, b0v.y, b0v.z, b0v.w, b1v.x, b1v.y, b1v.z, b1v.w};
#pragma unroll
      for (int j = 0; j < 8; ++j) {
        acc[0][j] += a0 * bv[j]; acc[1][j] += a1 * bv[j];
        acc[2][j] += a2 * bv[j]; acc[3][j] += a3 * bv[j];
      }
    }
    __syncthreads();
  }
  float* ob = outp + (size_t)bz * O3N + (size_t)c * NN + tn * 8;
#pragma unroll
  for (int i = 0; i < 4; ++i) {
    int g = g0 + to * 4 + i;
    float4 v0 = make_float4(acc[i][0], acc[i][1], acc[i][2], acc[i][3]);
    float4 v1 = make_float4(acc[i][4], acc[i][5], acc[i][6], acc[i][7]);
    float4* dst = (float4*)(ob + (size_t)g * 128);
    dst[0] = v0; dst[1] = v1;
  }
}

extern "C" void kernel_launch(void* const* d_in, const int* in_sizes, int n_in,
                              void* d_out, int out_size, void* d_ws, size_t ws_size,
                              hipStream_t stream) {
  (void)in_sizes; (void)n_in; (void)out_size;
  const float* x     = (const float*)d_in[0];
  const float* lnw   = (const float*)d_in[1];
  const float* lnb   = (const float*)d_in[2];
  const float* qkvw  = (const float*)d_in[3];
  const float* qkvb  = (const float*)d_in[4];
  const float* dww   = (const float*)d_in[5];
  const float* dwb   = (const float*)d_in[6];
  const float* projw = (const float*)d_in[7];
  const float* projb = (const float*)d_in[8];
  const float* temp1 = (const float*)d_in[9];
  const float* temp2 = (const float*)d_in[10];
  float* out = (float*)d_out;
  float* ws = (float*)d_ws;

  // small buffers: mu, rs, qm, km, attn (131072 fl each) + S(384) + bias2(384)
  // + Aq (49152 bf16 = 24576 fl) + Ap (16384 bf16 = 8192 fl)
  const size_t EXTRA = 5ull * 131072 + 384 + 384 + 24576 + 8192;
  auto needBytes = [&](int nb) { return ((size_t)nb * O3N + EXTRA) * 4; };
  int NB = 8;
  while (NB > 1 && ws_size < needBytes(NB)) NB >>= 1;
  if (ws_size < needBytes(1)) return;

  float* convbuf = ws;                       // NB*O3N: conv -> qkv (in-place dwc) -> q-region reused as tmp
  float* mu   = convbuf + (size_t)NB * O3N;
  float* rs   = mu + 131072;
  float* qm   = rs + 131072;
  float* km   = qm + 131072;
  float* attn = km + 131072;
  float* Svec  = attn + 131072;
  float* bias2 = Svec + 384;
  unsigned short* Aq = (unsigned short*)(bias2 + 384);
  unsigned short* Ap = Aq + 49152;

  k_prep<<<512, 64, 0, stream>>>(qkvw, qkvb, lnw, lnb, projw, Aq, Ap, Svec, bias2);

  for (int stage = 0; stage < 2; ++stage) {
    const float* src = stage ? out : x;
    k_stats<<<512, 256, 0, stream>>>(src, mu, rs);
    for (int b0 = 0; b0 < 8; b0 += NB) {
      k_qkv_mfma<<<dim3(256, 1, NB), 256, 0, stream>>>(src, mu, rs, Aq, Svec, bias2, convbuf, b0);
      k_dwc_ip<<<dim3(384, NB), 1024, 0, stream>>>(convbuf, dww, dwb);
      if (stage == 0)
        k_reduce1<<<dim3(64, NB), 256, 0, stream>>>(convbuf, qm, km, b0);
      else
        k_reduce2<<<dim3(64, NB), 256, 0, stream>>>(convbuf, qm, km, b0);
      k_norm2<<<dim3(NB * 128, 2), 64, 0, stream>>>(qm, km, b0 * 128);
      if (stage == 0)
        k_attn1<<<dim3(128, NB), 128, 0, stream>>>(qm, km, temp1, attn, b0);
      else
        k_attn2<<<dim3(128, NB), 128, 0, stream>>>(qm, km, temp2, attn, b0);
      if (stage == 0)
        k_apply1<<<dim3(256, 1, NB), 256, 0, stream>>>(convbuf, attn, convbuf, b0);
      else
        k_apply2<<<dim3(2, 128, NB), 256, 0, stream>>>(convbuf, attn, convbuf, b0);
      const float* resp = stage ? out : x;
      k_proj_mfma<<<dim3(256, 1, NB), 256, 0, stream>>>(convbuf, Ap, projb, resp, out, b0);
    }
  }
}

// Round 4
// 319.613 us; speedup vs baseline: 6.3785x; 1.7816x over previous
//
#include <hip/hip_runtime.h>

typedef __attribute__((ext_vector_type(8))) short bf16x8;
typedef __attribute__((ext_vector_type(4))) float f32x4;
typedef __attribute__((ext_vector_type(4))) unsigned short us4;
typedef __attribute__((ext_vector_type(4))) unsigned int u32x4;

// dims
static constexpr int CC = 128, NN = 16384;       // C, H*W (H=W=128)
static constexpr int O3 = 384;                   // 3*C
static constexpr long long CN  = (long long)CC * NN;   // 2097152
static constexpr long long O3N = (long long)O3 * NN;   // 6291456

__device__ __forceinline__ float wave_sum(float v) {
  for (int o = 32; o; o >>= 1) v += __shfl_xor(v, o);
  return v;
}
__device__ __forceinline__ float wave_max(float v) {
  for (int o = 32; o; o >>= 1) v = fmaxf(v, __shfl_xor(v, o));
  return v;
}
__device__ __forceinline__ unsigned short f2bf(float f) {
  unsigned u = __float_as_uint(f);
  u += 0x7FFF + ((u >> 16) & 1);            // RNE
  return (unsigned short)(u >> 16);
}
__device__ __forceinline__ float bf2f(unsigned short h) {
  return __uint_as_float((unsigned)h << 16);
}

// ---- prep: A' = bf16(W*lnw), S[o] = sum(A'), bias2[o] = bq + sum(W*lnb); proj W -> bf16 ----
__global__ __launch_bounds__(64) void k_prep(const float* __restrict__ qkvw,
                                             const float* __restrict__ qkvb,
                                             const float* __restrict__ lnw,
                                             const float* __restrict__ lnb,
                                             const float* __restrict__ projw,
                                             unsigned short* __restrict__ Aq,
                                             unsigned short* __restrict__ Ap,
                                             float* __restrict__ Svec,
                                             float* __restrict__ bias2) {
  int o = blockIdx.x, t = threadIdx.x;
  if (o < O3) {
    float w0 = qkvw[o * 128 + t], w1 = qkvw[o * 128 + t + 64];
    unsigned short h0 = f2bf(w0 * lnw[t]), h1 = f2bf(w1 * lnw[t + 64]);
    Aq[o * 128 + t] = h0; Aq[o * 128 + t + 64] = h1;
    float s = wave_sum(bf2f(h0) + bf2f(h1));
    float bs = wave_sum(w0 * lnb[t] + w1 * lnb[t + 64]);
    if (t == 0) { Svec[o] = s; bias2[o] = qkvb[o] + bs; }
  } else {
    int r = o - O3;
    Ap[r * 128 + t] = f2bf(projw[r * 128 + t]);
    Ap[r * 128 + t + 64] = f2bf(projw[r * 128 + t + 64]);
  }
}

// ---- per-pixel LN stats over channels (stage-1 only, reads x) ----
__global__ __launch_bounds__(256) void k_stats(const float* __restrict__ in,
                                               float* __restrict__ mu,
                                               float* __restrict__ rs) {
  int p = blockIdx.x * 256 + threadIdx.x;          // [0, B*N)
  int b = p >> 14, n = p & (NN - 1);
  const float* base = in + (size_t)b * CN + n;
  float s1 = 0.f, s2 = 0.f;
#pragma unroll 8
  for (int c = 0; c < CC; ++c) { float v = base[(size_t)c * NN]; s1 += v; s2 += v * v; }
  float m = s1 * (1.f / CC);
  float var = s2 * (1.f / CC) - m * m;
  mu[p] = m;
  rs[p] = rsqrtf(var + 1e-5f);
}

// ---- MFMA qkv GEMM with folded LN epilogue, bf16 output ----
// out[bz,o,n] = bf16( rs[n]*(sum_c A'[o,c]*x[c,n] - mu[n]*S[o]) + bias2[o] )
__global__ __launch_bounds__(256) void k_qkv_mfma(
    const float* __restrict__ x, const float* __restrict__ mu, const float* __restrict__ rs,
    const unsigned short* __restrict__ Aq, const float* __restrict__ Svec,
    const float* __restrict__ bias2, unsigned short* __restrict__ out, int b0) {
  __shared__ unsigned short Bs[64 * 136];          // [n][c] transposed
  __shared__ unsigned short As[384 * 40];          // [o][cc] per k-step
  int bz = blockIdx.z, bg = b0 + bz;
  int n0 = blockIdx.x * 64;
  int t = threadIdx.x, w = t >> 6, l = t & 63;
  int lr = l & 15, lg = l >> 4;
  const float* xb = x + (size_t)bg * CN + n0;

  {
    int cg = t >> 4, nl = t & 15;
#pragma unroll
    for (int r = 0; r < 8; ++r) {
      int c = r * 16 + cg;
      const float* src = xb + (size_t)c * NN + nl;
#pragma unroll
      for (int q = 0; q < 4; ++q)
        Bs[(nl + q * 16) * 136 + c] = f2bf(src[q * 16]);
    }
  }

  f32x4 acc[6][4];
#pragma unroll
  for (int i = 0; i < 6; ++i)
#pragma unroll
    for (int j = 0; j < 4; ++j) acc[i][j] = (f32x4){0.f, 0.f, 0.f, 0.f};

  const unsigned int* Asrc = (const unsigned int*)Aq;
  unsigned int* Adst = (unsigned int*)As;
  for (int ks = 0; ks < 4; ++ks) {
    __syncthreads();
#pragma unroll
    for (int r = 0; r < 24; ++r) {
      int idx = r * 256 + t;
      int o = idx >> 4, cp = idx & 15;
      Adst[o * 20 + cp] = Asrc[(size_t)o * 64 + ks * 16 + cp];
    }
    __syncthreads();
    bf16x8 bfr[4];
#pragma unroll
    for (int j = 0; j < 4; ++j)
      bfr[j] = *(const bf16x8*)&Bs[(16 * j + lr) * 136 + ks * 32 + lg * 8];
#pragma unroll
    for (int i = 0; i < 6; ++i) {
      bf16x8 afr = *(const bf16x8*)&As[(96 * w + 16 * i + lr) * 40 + lg * 8];
#pragma unroll
      for (int j = 0; j < 4; ++j)
        acc[i][j] = __builtin_amdgcn_mfma_f32_16x16x32_bf16(afr, bfr[j], acc[i][j], 0, 0, 0);
    }
  }

  float rsv[4], muv[4];
#pragma unroll
  for (int j = 0; j < 4; ++j) {
    int n = n0 + 16 * j + lr;
    rsv[j] = rs[(size_t)bg * NN + n];
    muv[j] = mu[(size_t)bg * NN + n];
  }
#pragma unroll
  for (int i = 0; i < 6; ++i) {
    int ob = 96 * w + 16 * i + lg * 4;
    float sv[4], bv[4];
#pragma unroll
    for (int r2 = 0; r2 < 4; ++r2) { sv[r2] = Svec[ob + r2]; bv[r2] = bias2[ob + r2]; }
#pragma unroll
    for (int j = 0; j < 4; ++j) {
      int n = n0 + 16 * j + lr;
      unsigned short* op = out + (size_t)bz * O3N + n;
#pragma unroll
      for (int r2 = 0; r2 < 4; ++r2)
        op[(size_t)(ob + r2) * NN] = f2bf(rsv[j] * (acc[i][j][r2] - muv[j] * sv[r2]) + bv[r2]);
    }
  }
}

// ---- 3x3 depthwise conv, bf16 in/out, padded-LDS, fused stage-1 reductions ----
// stage==0: q-ch (o<128) -> column mean over h -> qm rows; k-ch -> column max -> km rows;
//           v-ch -> bf16 plane in place.  stage==1: all channels write bf16 planes.
__global__ __launch_bounds__(1024) void k_dwc(unsigned short* __restrict__ buf,
                                              const float* __restrict__ dww,
                                              const float* __restrict__ dwb,
                                              float* __restrict__ qm,
                                              float* __restrict__ km,
                                              int b0, int stage) {
  __shared__ unsigned short pl[130 * 144];         // zero-padded plane (rows -1..128, cols -8..135)
  __shared__ float red[32 * 128];
  int o = blockIdx.x, bz = blockIdx.y, bg = b0 + bz;
  int t = threadIdx.x;
  unsigned short* base = buf + (size_t)bz * O3N + (size_t)o * NN;

  for (int i = t; i < 9360; i += 1024) ((unsigned*)pl)[i] = 0u;
  __syncthreads();
#pragma unroll
  for (int r = 0; r < 2; ++r) {
    int idx = r * 1024 + t;
    int row = idx >> 4, c8 = (idx & 15) * 8;
    *(u32x4*)&pl[(row + 1) * 144 + 8 + c8] = *(const u32x4*)&base[row * 128 + c8];
  }
  __syncthreads();

  const float* wg = dww + o * 9;
  float w00 = wg[0], w01 = wg[1], w02 = wg[2];
  float w10 = wg[3], w11 = wg[4], w12 = wg[5];
  float w20 = wg[6], w21 = wg[7], w22 = wg[8];
  float bias = dwb[o];
  int mode = (stage == 0) ? (o < 128 ? 1 : (o < 256 ? 2 : 0)) : 0;
  int hh0 = t >> 5, w0 = (t & 31) * 4;
  float csum[4] = {0.f, 0.f, 0.f, 0.f};
  float cmax[4] = {-1e30f, -1e30f, -1e30f, -1e30f};

#pragma unroll
  for (int g = 0; g < 4; ++g) {
    int h = g * 32 + hh0;
    float a0 = bias, a1 = bias, a2 = bias, a3 = bias;
#pragma unroll
    for (int dr = 0; dr < 3; ++dr) {
      const unsigned short* rp = &pl[(h + dr) * 144];
      us4 cA = *(const us4*)&rp[w0 + 4];
      us4 cB = *(const us4*)&rp[w0 + 8];
      us4 cC = *(const us4*)&rp[w0 + 12];
      float f0 = bf2f(cA[3]), f1 = bf2f(cB[0]), f2 = bf2f(cB[1]);
      float f3 = bf2f(cB[2]), f4 = bf2f(cB[3]), f5 = bf2f(cC[0]);
      float wr0 = (dr == 0) ? w00 : (dr == 1 ? w10 : w20);
      float wr1 = (dr == 0) ? w01 : (dr == 1 ? w11 : w21);
      float wr2 = (dr == 0) ? w02 : (dr == 1 ? w12 : w22);
      a0 += f0 * wr0 + f1 * wr1 + f2 * wr2;
      a1 += f1 * wr0 + f2 * wr1 + f3 * wr2;
      a2 += f2 * wr0 + f3 * wr1 + f4 * wr2;
      a3 += f3 * wr0 + f4 * wr1 + f5 * wr2;
    }
    if (mode == 0) {
      us4 ov;
      ov[0] = f2bf(a0); ov[1] = f2bf(a1); ov[2] = f2bf(a2); ov[3] = f2bf(a3);
      *(us4*)&base[g * 4096 + t * 4] = ov;
    } else if (mode == 1) {
      csum[0] += a0; csum[1] += a1; csum[2] += a2; csum[3] += a3;
    } else {
      cmax[0] = fmaxf(cmax[0], a0); cmax[1] = fmaxf(cmax[1], a1);
      cmax[2] = fmaxf(cmax[2], a2); cmax[3] = fmaxf(cmax[3], a3);
    }
  }

  if (mode) {
    int j = t >> 5;
#pragma unroll
    for (int dx = 0; dx < 4; ++dx)
      red[j * 128 + w0 + dx] = (mode == 1) ? csum[dx] : cmax[dx];
    __syncthreads();
    if (t < 128) {
      float v = red[t];
      if (mode == 1) {
        for (int jj = 1; jj < 32; ++jj) v += red[jj * 128 + t];
        qm[(size_t)bg * NN + o * 128 + t] = v * (1.f / 128.f);
      } else {
        for (int jj = 1; jj < 32; ++jj) v = fmaxf(v, red[jj * 128 + t]);
        km[(size_t)bg * NN + (o - 128) * 128 + t] = v;
      }
    }
  }
}

// ---- stage-2 reductions: mean over channels of bf16 q,k planes -> [b, h, w] ----
__global__ __launch_bounds__(256) void k_reduce2(const unsigned short* __restrict__ qkv,
                                                 float* __restrict__ qm, float* __restrict__ km,
                                                 int b0) {
  int bz = blockIdx.y;
  int n = blockIdx.x * 256 + threadIdx.x;
  const unsigned short* base = qkv + (size_t)bz * O3N + n;
  float sq = 0.f, sk = 0.f;
#pragma unroll 4
  for (int c = 0; c < 128; ++c) {
    sq += bf2f(base[(size_t)c * NN]);
    sk += bf2f(base[(size_t)(c + 128) * NN]);
  }
  size_t off = (size_t)(b0 + bz) * NN + n;
  qm[off] = sq * (1.f / 128.f);
  km[off] = sk * (1.f / 128.f);
}

// ---- l2-normalize rows of length 128 in place ----
__global__ void k_norm2(float* __restrict__ qm, float* __restrict__ km, int row0) {
  float* buf = blockIdx.y ? km : qm;
  int r = row0 + blockIdx.x, t = threadIdx.x;   // 64 threads
  float* p = buf + (size_t)r * 128;
  float v0 = p[t], v1 = p[t + 64];
  float s = wave_sum(v0 * v0 + v1 * v1);
  float sc = 1.f / fmaxf(sqrtf(s), 1e-12f);
  p[t] = v0 * sc;
  p[t + 64] = v1 * sc;
}

// ---- attn1: scores over c; writes attnT[v][w] bf16 ----
__global__ void k_attn1(const float* __restrict__ qm, const float* __restrict__ km,
                        const float* __restrict__ temp, unsigned short* __restrict__ attnT,
                        int b0) {
  int bg = b0 + blockIdx.y;
  int i = blockIdx.x, t = threadIdx.x;          // i = w (query), t = v (key)
  const float* qb = qm + (size_t)bg * NN;
  const float* kb = km + (size_t)bg * NN;
  __shared__ float qcol[128];
  __shared__ float wred[2];
  qcol[t] = qb[t * 128 + i];
  __syncthreads();
  float s = 0.f;
#pragma unroll 4
  for (int k = 0; k < 128; ++k) s += qcol[k] * kb[k * 128 + t];
  s *= temp[0];
  int wid = t >> 6, lane = t & 63;
  float mx = wave_max(s);
  if (lane == 0) wred[wid] = mx;
  __syncthreads();
  mx = fmaxf(wred[0], wred[1]);
  float pv = __expf(s - mx);
  __syncthreads();
  float sm = wave_sum(pv);
  if (lane == 0) wred[wid] = sm;
  __syncthreads();
  float denom = wred[0] + wred[1];
  attnT[(size_t)bg * NN + (size_t)t * 128 + i] = f2bf(pv / denom);
}

// ---- attn2: scores over w; writes attnT[g][h] bf16 ----
__global__ void k_attn2(const float* __restrict__ qm, const float* __restrict__ km,
                        const float* __restrict__ temp, unsigned short* __restrict__ attnT,
                        int b0) {
  int bg = b0 + blockIdx.y;
  int i = blockIdx.x, t = threadIdx.x;          // i = h, t = g
  const float* qb = qm + (size_t)bg * NN + i * 128;
  const float* kb = km + (size_t)bg * NN + (size_t)t * 128;
  __shared__ float qrow[128];
  __shared__ float wred[2];
  qrow[t] = qb[t];
  __syncthreads();
  float s = 0.f;
#pragma unroll 4
  for (int w = 0; w < 128; ++w) s += qrow[w] * kb[w];
  s *= temp[0];
  int wid = t >> 6, lane = t & 63;
  float mx = wave_max(s);
  if (lane == 0) wred[wid] = mx;
  __syncthreads();
  mx = fmaxf(wred[0], wred[1]);
  float pv = __expf(s - mx);
  __syncthreads();
  float sm = wave_sum(pv);
  if (lane == 0) wred[wid] = sm;
  __syncthreads();
  float denom = wred[0] + wred[1];
  attnT[(size_t)bg * NN + (size_t)t * 128 + i] = f2bf(pv / denom);
}

// ---- apply1 (MFMA): tmp[m=(c,h)][v] = sum_w v1[m][w] * attnT[v][w]; tmp = q-region bf16 ----
__global__ __launch_bounds__(256) void k_apply1_mfma(unsigned short* __restrict__ buf,
                                                     const unsigned short* __restrict__ attnT,
                                                     int b0) {
  __shared__ unsigned short Al[128 * 136];
  __shared__ unsigned short Bl[128 * 136];
  int bz = blockIdx.z, bg = b0 + bz;
  int m0 = blockIdx.x * 128;
  int t = threadIdx.x, w = t >> 6, l = t & 63, lr = l & 15, lg = l >> 4;
  const unsigned short* asrc = buf + (size_t)bz * O3N + (size_t)256 * NN + (size_t)m0 * 128;
  const unsigned short* bsrc = attnT + (size_t)bg * NN;
#pragma unroll
  for (int r = 0; r < 8; ++r) {
    int idx = r * 256 + t;
    int row = idx >> 4, c8 = (idx & 15) * 8;
    *(u32x4*)&Al[row * 136 + c8] = *(const u32x4*)&asrc[row * 128 + c8];
    *(u32x4*)&Bl[row * 136 + c8] = *(const u32x4*)&bsrc[row * 128 + c8];
  }
  __syncthreads();
  f32x4 acc[2][8];
#pragma unroll
  for (int i = 0; i < 2; ++i)
#pragma unroll
    for (int j = 0; j < 8; ++j) acc[i][j] = (f32x4){0.f, 0.f, 0.f, 0.f};
#pragma unroll
  for (int ks = 0; ks < 4; ++ks) {
    bf16x8 bfr[8];
#pragma unroll
    for (int j = 0; j < 8; ++j)
      bfr[j] = *(const bf16x8*)&Bl[(16 * j + lr) * 136 + ks * 32 + lg * 8];
#pragma unroll
    for (int i = 0; i < 2; ++i) {
      bf16x8 afr = *(const bf16x8*)&Al[(32 * w + 16 * i + lr) * 136 + ks * 32 + lg * 8];
#pragma unroll
      for (int j = 0; j < 8; ++j)
        acc[i][j] = __builtin_amdgcn_mfma_f32_16x16x32_bf16(afr, bfr[j], acc[i][j], 0, 0, 0);
    }
  }
  unsigned short* ob = buf + (size_t)bz * O3N;   // q-region alias
#pragma unroll
  for (int i = 0; i < 2; ++i)
#pragma unroll
    for (int j = 0; j < 8; ++j)
#pragma unroll
      for (int r2 = 0; r2 < 4; ++r2) {
        int m = m0 + 32 * w + 16 * i + lg * 4 + r2;
        int n = 16 * j + lr;
        ob[(size_t)m * 128 + n] = f2bf(acc[i][j][r2]);
      }
}

// ---- apply2 (MFMA): tmp[c][g*128+w] = sum_h attnT[g][h] * v2plane[h][w] ----
__global__ __launch_bounds__(256) void k_apply2_mfma(unsigned short* __restrict__ buf,
                                                     const unsigned short* __restrict__ attnT,
                                                     int b0) {
  __shared__ unsigned short At[128 * 136];
  __shared__ unsigned short Bt[128 * 136];       // v2 plane transposed [w][h]
  int bz = blockIdx.z, bg = b0 + bz, c = blockIdx.x;
  int t = threadIdx.x, w = t >> 6, l = t & 63, lr = l & 15, lg = l >> 4;
  const unsigned short* vsrc = buf + (size_t)bz * O3N + (size_t)(256 + c) * NN;
  const unsigned short* asrc = attnT + (size_t)bg * NN;
#pragma unroll
  for (int r = 0; r < 8; ++r) {
    int idx = r * 256 + t;
    int row = idx >> 4, c8 = (idx & 15) * 8;
    *(u32x4*)&At[row * 136 + c8] = *(const u32x4*)&asrc[row * 128 + c8];
    us4 lo = *(const us4*)&vsrc[row * 128 + c8];
    us4 hi = *(const us4*)&vsrc[row * 128 + c8 + 4];
#pragma unroll
    for (int q = 0; q < 4; ++q) {
      Bt[(c8 + q) * 136 + row] = lo[q];
      Bt[(c8 + 4 + q) * 136 + row] = hi[q];
    }
  }
  __syncthreads();
  f32x4 acc[2][8];
#pragma unroll
  for (int i = 0; i < 2; ++i)
#pragma unroll
    for (int j = 0; j < 8; ++j) acc[i][j] = (f32x4){0.f, 0.f, 0.f, 0.f};
#pragma unroll
  for (int ks = 0; ks < 4; ++ks) {
    bf16x8 bfr[8];
#pragma unroll
    for (int j = 0; j < 8; ++j)
      bfr[j] = *(const bf16x8*)&Bt[(16 * j + lr) * 136 + ks * 32 + lg * 8];
#pragma unroll
    for (int i = 0; i < 2; ++i) {
      bf16x8 afr = *(const bf16x8*)&At[(32 * w + 16 * i + lr) * 136 + ks * 32 + lg * 8];
#pragma unroll
      for (int j = 0; j < 8; ++j)
        acc[i][j] = __builtin_amdgcn_mfma_f32_16x16x32_bf16(afr, bfr[j], acc[i][j], 0, 0, 0);
    }
  }
  unsigned short* ob = buf + (size_t)bz * O3N + (size_t)c * NN;  // q-region plane c
#pragma unroll
  for (int i = 0; i < 2; ++i)
#pragma unroll
    for (int j = 0; j < 8; ++j)
#pragma unroll
      for (int r2 = 0; r2 < 4; ++r2) {
        int g = 32 * w + 16 * i + lg * 4 + r2;
        int n = 16 * j + lr;
        ob[(size_t)g * 128 + n] = f2bf(acc[i][j][r2]);
      }
}

// ---- proj (MFMA) + residual; optional fused LN stats of the output (stage 1) ----
__global__ __launch_bounds__(256) void k_proj_mfma(
    const unsigned short* __restrict__ tin, const unsigned short* __restrict__ Ap,
    const float* __restrict__ pb, const float* __restrict__ res,
    float* __restrict__ dst, float* __restrict__ mu, float* __restrict__ rs,
    int b0, int do_stats) {
  __shared__ unsigned short Al[128 * 136];
  __shared__ unsigned short Bs2[64 * 136];
  __shared__ float red1[64 * 17];
  __shared__ float red2[64 * 17];
  int bz = blockIdx.z, bg = b0 + bz;
  int n0 = blockIdx.x * 64;
  int t = threadIdx.x, w = t >> 6, l = t & 63, lr = l & 15, lg = l >> 4;
  const unsigned short* tb = tin + (size_t)bz * O3N;
#pragma unroll
  for (int r = 0; r < 8; ++r) {
    int idx = r * 256 + t;
    int row = idx >> 4, c8 = (idx & 15) * 8;
    *(u32x4*)&Al[row * 136 + c8] = *(const u32x4*)&Ap[row * 128 + c8];
  }
#pragma unroll
  for (int r = 0; r < 32; ++r) {
    int idx = r * 256 + t;
    int cI = idx >> 6, nI = idx & 63;
    Bs2[nI * 136 + cI] = tb[(size_t)cI * NN + n0 + nI];
  }
  __syncthreads();

  f32x4 acc[2][4];
#pragma unroll
  for (int i = 0; i < 2; ++i)
#pragma unroll
    for (int j = 0; j < 4; ++j) acc[i][j] = (f32x4){0.f, 0.f, 0.f, 0.f};
#pragma unroll
  for (int ks = 0; ks < 4; ++ks) {
    bf16x8 bfr[4];
#pragma unroll
    for (int j = 0; j < 4; ++j)
      bfr[j] = *(const bf16x8*)&Bs2[(16 * j + lr) * 136 + ks * 32 + lg * 8];
#pragma unroll
    for (int i = 0; i < 2; ++i) {
      bf16x8 afr = *(const bf16x8*)&Al[(32 * w + 16 * i + lr) * 136 + ks * 32 + lg * 8];
#pragma unroll
      for (int j = 0; j < 4; ++j)
        acc[i][j] = __builtin_amdgcn_mfma_f32_16x16x32_bf16(afr, bfr[j], acc[i][j], 0, 0, 0);
    }
  }

  float s1p[4] = {0.f, 0.f, 0.f, 0.f}, s2p[4] = {0.f, 0.f, 0.f, 0.f};
#pragma unroll
  for (int i = 0; i < 2; ++i) {
    int ob = 32 * w + 16 * i + lg * 4;
    float bv[4];
#pragma unroll
    for (int r2 = 0; r2 < 4; ++r2) bv[r2] = pb[ob + r2];
#pragma unroll
    for (int j = 0; j < 4; ++j) {
      int n = n0 + 16 * j + lr;
#pragma unroll
      for (int r2 = 0; r2 < 4; ++r2) {
        size_t off = (size_t)bg * CN + (size_t)(ob + r2) * NN + n;
        float val = acc[i][j][r2] + bv[r2] + res[off];
        dst[off] = val;
        s1p[j] += val;
        s2p[j] += val * val;
      }
    }
  }
  if (do_stats) {
#pragma unroll
    for (int j = 0; j < 4; ++j) {
      red1[(16 * j + lr) * 17 + (w * 4 + lg)] = s1p[j];
      red2[(16 * j + lr) * 17 + (w * 4 + lg)] = s2p[j];
    }
    __syncthreads();
    if (t < 64) {
      float s1 = 0.f, s2 = 0.f;
#pragma unroll
      for (int kk = 0; kk < 16; ++kk) { s1 += red1[t * 17 + kk]; s2 += red2[t * 17 + kk]; }
      float m = s1 * (1.f / 128.f);
      float var = s2 * (1.f / 128.f) - m * m;
      mu[(size_t)bg * NN + n0 + t] = m;
      rs[(size_t)bg * NN + n0 + t] = rsqrtf(var + 1e-5f);
    }
  }
}

extern "C" void kernel_launch(void* const* d_in, const int* in_sizes, int n_in,
                              void* d_out, int out_size, void* d_ws, size_t ws_size,
                              hipStream_t stream) {
  (void)in_sizes; (void)n_in; (void)out_size;
  const float* x     = (const float*)d_in[0];
  const float* lnw   = (const float*)d_in[1];
  const float* lnb   = (const float*)d_in[2];
  const float* qkvw  = (const float*)d_in[3];
  const float* qkvb  = (const float*)d_in[4];
  const float* dww   = (const float*)d_in[5];
  const float* dwb   = (const float*)d_in[6];
  const float* projw = (const float*)d_in[7];
  const float* projb = (const float*)d_in[8];
  const float* temp1 = (const float*)d_in[9];
  const float* temp2 = (const float*)d_in[10];
  float* out = (float*)d_out;
  float* ws = (float*)d_ws;

  // floats: convbuf(bf16) NB*O3N/2 + mu,rs,qm,km (4*131072) + attnT bf16 (65536)
  //         + Svec/bias2 (768) + Aq (24576) + Ap (8192)
  auto needBytes = [&](int nb) {
    return ((size_t)nb * (O3N / 2) + 4ull * 131072 + 65536 + 768 + 24576 + 8192) * 4;
  };
  int NB = 8;
  while (NB > 1 && ws_size < needBytes(NB)) NB >>= 1;
  if (ws_size < needBytes(1)) return;

  unsigned short* convbuf = (unsigned short*)ws;
  float* mu = ws + (size_t)NB * (O3N / 2);
  float* rs = mu + 131072;
  float* qm = rs + 131072;
  float* km = qm + 131072;
  unsigned short* attnT = (unsigned short*)(km + 131072);
  float* Svec  = (float*)(attnT + 8ull * NN);
  float* bias2 = Svec + 384;
  unsigned short* Aq = (unsigned short*)(bias2 + 384);
  unsigned short* Ap = Aq + 49152;

  k_prep<<<512, 64, 0, stream>>>(qkvw, qkvb, lnw, lnb, projw, Aq, Ap, Svec, bias2);
  k_stats<<<512, 256, 0, stream>>>(x, mu, rs);   // stage-2 stats fused into stage-1 proj

  for (int stage = 0; stage < 2; ++stage) {
    const float* src = stage ? out : x;
    for (int b0 = 0; b0 < 8; b0 += NB) {
      k_qkv_mfma<<<dim3(256, 1, NB), 256, 0, stream>>>(src, mu, rs, Aq, Svec, bias2, convbuf, b0);
      k_dwc<<<dim3(384, NB), 1024, 0, stream>>>(convbuf, dww, dwb, qm, km, b0, stage);
      if (stage == 1)
        k_reduce2<<<dim3(64, NB), 256, 0, stream>>>(convbuf, qm, km, b0);
      k_norm2<<<dim3(NB * 128, 2), 64, 0, stream>>>(qm, km, b0 * 128);
      if (stage == 0)
        k_attn1<<<dim3(128, NB), 128, 0, stream>>>(qm, km, temp1, attnT, b0);
      else
        k_attn2<<<dim3(128, NB), 128, 0, stream>>>(qm, km, temp2, attnT, b0);
      if (stage == 0)
        k_apply1_mfma<<<dim3(128, 1, NB), 256, 0, stream>>>(convbuf, attnT, b0);
      else
        k_apply2_mfma<<<dim3(128, 1, NB), 256, 0, stream>>>(convbuf, attnT, b0);
      const float* resp = stage ? out : x;
      k_proj_mfma<<<dim3(256, 1, NB), 256, 0, stream>>>(convbuf, Ap, projb, resp, out,
                                                        mu, rs, b0, stage == 0 ? 1 : 0);
    }
  }
}